// Round 2
// baseline (1141.632 us; speedup 1.0000x reference)
//
#include <hip/hip_runtime.h>
#include <cstdint>
#include <cstddef>

typedef float f32x4 __attribute__((ext_vector_type(4)));
typedef __bf16 bf16x8 __attribute__((ext_vector_type(8)));
typedef unsigned short u16;

__device__ __forceinline__ float bf2f(u16 u) {
  union { unsigned int i; float f; } x; x.i = ((unsigned int)u) << 16; return x.f;
}
__device__ __forceinline__ u16 f2bf(float f) {
  union { float f; unsigned int i; } x; x.f = f;
  unsigned int i = x.i;
  i += 0x7fffu + ((i >> 16) & 1u);   // round-to-nearest-even
  return (u16)(i >> 16);
}

#if defined(__has_builtin)
#if __has_builtin(__builtin_amdgcn_global_load_lds)
#define HAS_GLL 1
#endif
#endif

__device__ __forceinline__ void async16(const u16* g, u16* l) {
#ifdef HAS_GLL
  __builtin_amdgcn_global_load_lds((const __attribute__((address_space(1))) void*)(const void*)g,
                                   (__attribute__((address_space(3))) void*)(void*)l, 16, 0, 0);
#else
  *(uint4*)l = *(const uint4*)g;
#endif
}

// ---------------- mask compaction (dtype-width-agnostic) ----------------
// Every row has length >= 512, so position s=1 is always valid: byte stride
// detect: bool/int8 -> mask[1]!=0 ; int32 -> mask[4]!=0 ; else int64.
__global__ void compact_mask(const unsigned char* __restrict__ mask,
                             int* __restrict__ padIdx, int* __restrict__ padCnt,
                             float* __restrict__ maskf) {
  const int b = blockIdx.x;        // 4 rows
  const int lane = threadIdx.x;    // 64
  int stride = 1;
  if (mask[1] == 0) stride = (mask[4] != 0) ? 4 : 8;
  int cnt = 0;
  for (int s0 = 0; s0 < 1024; s0 += 64) {
    const int s = s0 + lane;
    const bool valid = (mask[(size_t)((b << 10) + s) * stride] != 0);
    maskf[(b << 10) + s] = valid ? 1.f : 0.f;
    const bool pad = !valid;
    const unsigned long long bal = __ballot(pad);
    const int rank = (int)__popcll(bal & ((1ull << lane) - 1ull));
    if (pad) padIdx[(b << 10) + cnt + rank] = s;
    cnt += (int)__popcll(bal);
  }
  if (lane == 0) padCnt[b] = cnt;
}

// ---------------- fp32 -> bf16 convert ----------------
__global__ __launch_bounds__(256)
void f32_to_bf16(const float* __restrict__ in, u16* __restrict__ out, int n4) {
  const int i = blockIdx.x * 256 + threadIdx.x;
  if (i < n4) {
    const float4 v = ((const float4*)in)[i];
    u16 o[4] = { f2bf(v.x), f2bf(v.y), f2bf(v.z), f2bf(v.w) };
    ((ushort4*)out)[i] = *(const ushort4*)o;
  }
}

// ---------------- fp32 transpose+convert: in[R][C] f32 -> out[C][R] bf16 ----------------
__global__ __launch_bounds__(256)
void transpose_f32_bf16(const float* __restrict__ in, u16* __restrict__ out, int R, int C) {
  __shared__ u16 tile[64][65];
  const int r0 = blockIdx.y << 6, c0 = blockIdx.x << 6;
  const int tid = threadIdx.x;
  const int lr = tid >> 3, lc = (tid & 7) << 3;
#pragma unroll
  for (int p = 0; p < 2; ++p) {
    const int row = lr + (p << 5);
    const float4 a = *(const float4*)(in + (size_t)(r0 + row) * C + c0 + lc);
    const float4 bq = *(const float4*)(in + (size_t)(r0 + row) * C + c0 + lc + 4);
    tile[row][lc + 0] = f2bf(a.x); tile[row][lc + 1] = f2bf(a.y);
    tile[row][lc + 2] = f2bf(a.z); tile[row][lc + 3] = f2bf(a.w);
    tile[row][lc + 4] = f2bf(bq.x); tile[row][lc + 5] = f2bf(bq.y);
    tile[row][lc + 6] = f2bf(bq.z); tile[row][lc + 7] = f2bf(bq.w);
  }
  __syncthreads();
#pragma unroll
  for (int p = 0; p < 2; ++p) {
    const int oc = lr + (p << 5);
    u16 tmp[8];
#pragma unroll
    for (int e = 0; e < 8; ++e) tmp[e] = tile[lc + e][oc];
    *(uint4*)(out + (size_t)(c0 + oc) * R + r0 + lc) = *(const uint4*)tmp;
  }
}

// ---------------- GEMM: C[M,N] = A(taps)[M,K] @ B[K,N] (+bias, relu) ----------------
// A: [M, Korig] bf16 row-major; taps make virtual K = NTAPS*Korig with row shift t-1
// BT: [N, K] bf16 row-major (pre-transposed weights); bias fp32
template<int NTAPS, bool RELU>
__global__ __launch_bounds__(256)
void gemm_bt(const u16* __restrict__ A, const u16* __restrict__ BT,
             const float* __restrict__ bias, u16* __restrict__ C,
             int M, int N, int Korig, const u16* __restrict__ zp) {
  __shared__ __align__(16) u16 As[128 * 64];
  __shared__ __align__(16) u16 Bs[128 * 64];
  const int tid = threadIdx.x;
  const int m0 = blockIdx.y << 7;
  const int n0 = blockIdx.x << 7;
  const int Ktot = NTAPS * Korig;
  const int lane = tid & 63;
  const int w = tid >> 6;
  const int wm = (w >> 1) << 6;
  const int wn = (w & 1) << 6;
  const int fr = lane & 15;
  const int fko = (lane >> 4) << 3;
  const int srow = tid >> 3;          // 0..31
  const int scol = (tid & 7) << 3;    // 0..56

  f32x4 acc[4][4] = {};

  for (int k0 = 0; k0 < Ktot; k0 += 64) {
    int t = 0, c0 = k0;
    if (NTAPS == 3) { t = k0 / Korig; c0 = k0 - t * Korig; }
#pragma unroll
    for (int i = 0; i < 4; ++i) {
      const int row = srow + (i << 5);
      const u16* src;
      if (NTAPS == 3) {
        const int m = m0 + row;
        const int sp = (m & 1023) + t - 1;   // position within 1024-seq after shift
        src = ((unsigned)sp < 1024u) ? (A + (size_t)(m + t - 1) * Korig + c0 + scol)
                                     : (zp + ((tid & 255) << 3));
      } else {
        src = A + (size_t)(m0 + row) * Korig + c0 + scol;
      }
      async16(src, &As[(row << 6) + scol]);
    }
#pragma unroll
    for (int i = 0; i < 4; ++i) {
      const int n = srow + (i << 5);
      async16(BT + (size_t)(n0 + n) * Ktot + k0 + scol, &Bs[(n << 6) + scol]);
    }
    asm volatile("s_waitcnt vmcnt(0)" ::: "memory");
    __syncthreads();
#pragma unroll
    for (int ks = 0; ks < 64; ks += 32) {
      bf16x8 af[4], bfr[4];
#pragma unroll
      for (int mi = 0; mi < 4; ++mi)
        af[mi] = *(const bf16x8*)&As[((wm + (mi << 4) + fr) << 6) + ks + fko];
#pragma unroll
      for (int ni = 0; ni < 4; ++ni)
        bfr[ni] = *(const bf16x8*)&Bs[((wn + (ni << 4) + fr) << 6) + ks + fko];
#pragma unroll
      for (int mi = 0; mi < 4; ++mi)
#pragma unroll
        for (int ni = 0; ni < 4; ++ni)
          acc[mi][ni] = __builtin_amdgcn_mfma_f32_16x16x32_bf16(af[mi], bfr[ni], acc[mi][ni], 0, 0, 0);
    }
    __syncthreads();
  }
  // epilogue: D col = lane&15, row = (lane>>4)*4 + reg
  const int rbase = m0 + wm + ((lane >> 4) << 2);
  const int cbase = n0 + wn + fr;
#pragma unroll
  for (int ni = 0; ni < 4; ++ni) {
    const int col = cbase + (ni << 4);
    const float bv = bias ? bias[col] : 0.f;
#pragma unroll
    for (int mi = 0; mi < 4; ++mi) {
#pragma unroll
      for (int r = 0; r < 4; ++r) {
        float v = acc[mi][ni][r] + bv;
        if (RELU) v = fmaxf(v, 0.f);
        C[(size_t)(rbase + (mi << 4) + r) * N + col] = f2bf(v);
      }
    }
  }
}

// ---------------- attention over PAD keys only (faithful to mask bug) ----------------
// flat head i = b*16+h; mask batch = out batch = i&3; out head slot = i>>2
__global__ __launch_bounds__(256)
void attn_kernel(const u16* __restrict__ QKV, const int* __restrict__ padIdx,
                 const int* __restrict__ padCnt, u16* __restrict__ vecS) {
  __shared__ float kls[64][64];
  __shared__ float vls[64][64];
  const int i = blockIdx.x;
  const int b = i >> 4, h = i & 15;
  const int mb = i & 3, h_out = i >> 2;
  const int tid = threadIdx.x;
  const int q = (blockIdx.y << 8) + tid;
  const u16* qrow = QKV + (size_t)((b << 10) + q) * 3072 + (h << 6);
  float qv[64];
#pragma unroll
  for (int d = 0; d < 64; ++d) qv[d] = bf2f(qrow[d]);
  float mrun = -1e30f, lrun = 0.f;
  float acc[64];
#pragma unroll
  for (int d = 0; d < 64; ++d) acc[d] = 0.f;
  const int npad = padCnt[mb];
  const int jj = tid >> 2, d0 = (tid & 3) << 4;
  for (int base = 0; base < npad; base += 64) {
    const int rem = npad - base;
    const int lim = rem < 64 ? rem : 64;
    __syncthreads();
    if (jj < lim) {
      const int kidx = padIdx[(mb << 10) + base + jj];
      const u16* kr = QKV + (size_t)((b << 10) + kidx) * 3072 + 1024 + (h << 6) + d0;
      const u16* vr = kr + 1024;
#pragma unroll
      for (int e = 0; e < 16; ++e) { kls[jj][d0 + e] = bf2f(kr[e]); vls[jj][d0 + e] = bf2f(vr[e]); }
    }
    __syncthreads();
#pragma unroll 1
    for (int j = 0; j < lim; ++j) {
      float s = 0.f;
#pragma unroll
      for (int d = 0; d < 64; ++d) s += qv[d] * kls[j][d];
      s *= 0.125f;   // 1/sqrt(64); the +1.0 pad-bias is constant -> cancels in softmax
      const float mn = fmaxf(mrun, s);
      const float al = __expf(mrun - mn);
      const float p = __expf(s - mn);
      lrun = lrun * al + p;
#pragma unroll
      for (int d = 0; d < 64; ++d) acc[d] = acc[d] * al + p * vls[j][d];
      mrun = mn;
    }
  }
  const float inv = 1.f / lrun;
  u16* orow = vecS + (size_t)((mb << 10) + q) * 1024 + (h_out << 6);
#pragma unroll
  for (int d = 0; d < 64; ++d) orow[d] = f2bf(acc[d] * inv);
}

// ---------------- residual + layernorm + mask-mul ----------------
// XF32: residual X is fp32 (else bf16). OUTF32: write fp32 (else bf16).
template<bool XF32, bool OUTF32>
__global__ __launch_bounds__(256)
void ln_kernel(const void* __restrict__ Xv, const u16* __restrict__ Yd,
               const float* __restrict__ g, const float* __restrict__ be,
               const float* __restrict__ maskf, void* __restrict__ outv) {
  const int r = blockIdx.x;
  const int tid = threadIdx.x;
  const size_t base = (size_t)r << 10;
  const float* Xf = (const float*)Xv;
  const u16* Xb = (const u16*)Xv;
  float x[4];
  float s1 = 0.f, s2 = 0.f;
#pragma unroll
  for (int j = 0; j < 4; ++j) {
    const int c = (tid << 2) + j;
    const float xv = XF32 ? Xf[base + c] : bf2f(Xb[base + c]);
    const float v = xv + bf2f(Yd[base + c]);
    x[j] = v; s1 += v; s2 += v * v;
  }
#pragma unroll
  for (int off = 32; off > 0; off >>= 1) { s1 += __shfl_xor(s1, off, 64); s2 += __shfl_xor(s2, off, 64); }
  __shared__ float rs1[4], rs2[4];
  if ((tid & 63) == 0) { rs1[tid >> 6] = s1; rs2[tid >> 6] = s2; }
  __syncthreads();
  s1 = rs1[0] + rs1[1] + rs1[2] + rs1[3];
  s2 = rs2[0] + rs2[1] + rs2[2] + rs2[3];
  const float mean = s1 * (1.f / 1024.f);
  const float var = s2 * (1.f / 1024.f) - mean * mean;
  const float rstd = rsqrtf(var + 1e-3f);
  const float mv = maskf[r];
#pragma unroll
  for (int j = 0; j < 4; ++j) {
    const int c = (tid << 2) + j;
    const float y = ((x[j] - mean) * rstd * g[c] + be[c]) * mv;
    if (OUTF32) ((float*)outv)[base + c] = y;
    else ((u16*)outv)[base + c] = f2bf(y);
  }
}

extern "C" void kernel_launch(void* const* d_in, const int* in_sizes, int n_in,
                              void* d_out, int out_size, void* d_ws, size_t ws_size,
                              hipStream_t stream) {
  (void)in_sizes; (void)n_in; (void)out_size; (void)ws_size;
  const float* dec  = (const float*)d_in[0];
  const unsigned char* mask = (const unsigned char*)d_in[1];
  const float* wqkv = (const float*)d_in[2];
  const float* bqkv = (const float*)d_in[3];
  const float* wo   = (const float*)d_in[4];
  const float* g1   = (const float*)d_in[5];
  const float* b1   = (const float*)d_in[6];
  const float* w1   = (const float*)d_in[7];
  const float* bc1  = (const float*)d_in[8];
  const float* w2   = (const float*)d_in[9];
  const float* bc2  = (const float*)d_in[10];
  const float* g2   = (const float*)d_in[11];
  const float* b2   = (const float*)d_in[12];
  char* ws = (char*)d_ws;
  // workspace layout (bytes)
  u16*   zp    = (u16*)(ws + 0);            // 4 KB zero page (bf16 zeros)
  int*   pcnt  = (int*)(ws + 4096);
  float* maskf = (float*)(ws + 8192);       // [4096]
  int*   pidx  = (int*)(ws + 24576);        // [4][1024]
  u16*   decB  = (u16*)(ws + 65536);        // [4096][1024]   ends 8454144
  u16*   wqkvT = (u16*)(ws + 8454144);      // [3072][1024]   ends 14745600
  u16*   woT   = (u16*)(ws + 14745600);     // [1024][1024]   ends 16842752
  u16*   w1T   = (u16*)(ws + 16842752);     // [4096][3072]   ends 42008576
  u16*   w2T   = (u16*)(ws + 42008576);     // [1024][12288]  ends 67174400
  u16*   qkv   = (u16*)(ws + 67174400);     // [4096][3072]   ends 92340224
  u16*   vecS  = (u16*)(ws + 92340224);     // [4096][1024]   ends 100728832
  u16*   ybuf  = (u16*)(ws + 67174400);     // [4096][4096] aliases qkv+vecS (both dead by conv1)
  u16*   atto  = (u16*)(ws + 100728832);    // [4096][1024]   ends 109117440
  u16*   core  = (u16*)(ws + 100728832);    // aliases atto (dead after LN1)
  u16*   x1bf  = (u16*)(ws + 109117440);    // [4096][1024]   ends 117506048

  hipMemsetAsync(zp, 0, 4096, stream);
  compact_mask<<<dim3(4), dim3(64), 0, stream>>>(mask, pidx, pcnt, maskf);
  f32_to_bf16<<<dim3(4096), dim3(256), 0, stream>>>(dec, decB, 1048576);
  transpose_f32_bf16<<<dim3(48, 16), dim3(256), 0, stream>>>(wqkv, wqkvT, 1024, 3072);
  transpose_f32_bf16<<<dim3(16, 16), dim3(256), 0, stream>>>(wo, woT, 1024, 1024);
  transpose_f32_bf16<<<dim3(64, 48), dim3(256), 0, stream>>>(w1, w1T, 3072, 4096);
  transpose_f32_bf16<<<dim3(16, 192), dim3(256), 0, stream>>>(w2, w2T, 12288, 1024);
  // qkv = dec @ qkv_w + qkv_b
  gemm_bt<1, false><<<dim3(24, 32), dim3(256), 0, stream>>>(decB, wqkvT, bqkv, qkv, 4096, 3072, 1024, zp);
  // attention (pad-keys-only, scrambled output)
  attn_kernel<<<dim3(64, 4), dim3(256), 0, stream>>>(qkv, pidx, pcnt, vecS);
  // attn_out = vecS @ o_w
  gemm_bt<1, false><<<dim3(8, 32), dim3(256), 0, stream>>>(vecS, woT, nullptr, atto, 4096, 1024, 1024, zp);
  // x1 = LN1(dec + attn_out) * mask   (dec residual read in fp32)
  ln_kernel<true, false><<<dim3(4096), dim3(256), 0, stream>>>(dec, atto, g1, b1, maskf, x1bf);
  // y = relu(conv1(x1))
  gemm_bt<3, true><<<dim3(32, 32), dim3(256), 0, stream>>>(x1bf, w1T, bc1, ybuf, 4096, 4096, 1024, zp);
  // core = conv2(y)
  gemm_bt<3, false><<<dim3(8, 32), dim3(256), 0, stream>>>(ybuf, w2T, bc2, core, 4096, 1024, 4096, zp);
  // out = LN2(x1 + core) * mask  -> fp32 d_out
  ln_kernel<false, true><<<dim3(4096), dim3(256), 0, stream>>>(x1bf, core, g2, b2, maskf, (float*)d_out);
}

// Round 3
// 769.779 us; speedup vs baseline: 1.4831x; 1.4831x over previous
//
#include <hip/hip_runtime.h>
#include <cstdint>
#include <cstddef>

typedef float f32x4 __attribute__((ext_vector_type(4)));
typedef __bf16 bf16x8 __attribute__((ext_vector_type(8)));
typedef unsigned short u16;

__device__ __forceinline__ float bf2f(u16 u) {
  union { unsigned int i; float f; } x; x.i = ((unsigned int)u) << 16; return x.f;
}
__device__ __forceinline__ u16 f2bf(float f) {
  union { float f; unsigned int i; } x; x.f = f;
  unsigned int i = x.i;
  i += 0x7fffu + ((i >> 16) & 1u);   // round-to-nearest-even
  return (u16)(i >> 16);
}

#if defined(__has_builtin)
#if __has_builtin(__builtin_amdgcn_global_load_lds)
#define HAS_GLL 1
#endif
#endif

__device__ __forceinline__ void async16(const u16* g, u16* l) {
#ifdef HAS_GLL
  __builtin_amdgcn_global_load_lds((const __attribute__((address_space(1))) void*)(const void*)g,
                                   (__attribute__((address_space(3))) void*)(void*)l, 16, 0, 0);
#else
  *(uint4*)l = *(const uint4*)g;
#endif
}

// ---------------- mask compaction (dtype-width-agnostic) ----------------
__global__ void compact_mask(const unsigned char* __restrict__ mask,
                             int* __restrict__ padIdx, int* __restrict__ padCnt,
                             float* __restrict__ maskf) {
  const int b = blockIdx.x;        // 4 rows
  const int lane = threadIdx.x;    // 64
  int stride = 1;
  if (mask[1] == 0) stride = (mask[4] != 0) ? 4 : 8;
  int cnt = 0;
  for (int s0 = 0; s0 < 1024; s0 += 64) {
    const int s = s0 + lane;
    const bool valid = (mask[(size_t)((b << 10) + s) * stride] != 0);
    maskf[(b << 10) + s] = valid ? 1.f : 0.f;
    const bool pad = !valid;
    const unsigned long long bal = __ballot(pad);
    const int rank = (int)__popcll(bal & ((1ull << lane) - 1ull));
    if (pad) padIdx[(b << 10) + cnt + rank] = s;
    cnt += (int)__popcll(bal);
  }
  if (lane == 0) padCnt[b] = cnt;
}

// ---------------- fp32 -> bf16 convert ----------------
__global__ __launch_bounds__(256)
void f32_to_bf16(const float* __restrict__ in, u16* __restrict__ out, int n4) {
  const int i = blockIdx.x * 256 + threadIdx.x;
  if (i < n4) {
    const float4 v = ((const float4*)in)[i];
    u16 o[4] = { f2bf(v.x), f2bf(v.y), f2bf(v.z), f2bf(v.w) };
    ((ushort4*)out)[i] = *(const ushort4*)o;
  }
}

// ---------------- fp32 transpose+convert: in[R][C] f32 -> out[C][R] bf16 ----------------
__global__ __launch_bounds__(256)
void transpose_f32_bf16(const float* __restrict__ in, u16* __restrict__ out, int R, int C) {
  __shared__ u16 tile[64][65];
  const int r0 = blockIdx.y << 6, c0 = blockIdx.x << 6;
  const int tid = threadIdx.x;
  const int lr = tid >> 3, lc = (tid & 7) << 3;
#pragma unroll
  for (int p = 0; p < 2; ++p) {
    const int row = lr + (p << 5);
    const float4 a = *(const float4*)(in + (size_t)(r0 + row) * C + c0 + lc);
    const float4 bq = *(const float4*)(in + (size_t)(r0 + row) * C + c0 + lc + 4);
    tile[row][lc + 0] = f2bf(a.x); tile[row][lc + 1] = f2bf(a.y);
    tile[row][lc + 2] = f2bf(a.z); tile[row][lc + 3] = f2bf(a.w);
    tile[row][lc + 4] = f2bf(bq.x); tile[row][lc + 5] = f2bf(bq.y);
    tile[row][lc + 6] = f2bf(bq.z); tile[row][lc + 7] = f2bf(bq.w);
  }
  __syncthreads();
#pragma unroll
  for (int p = 0; p < 2; ++p) {
    const int oc = lr + (p << 5);
    u16 tmp[8];
#pragma unroll
    for (int e = 0; e < 8; ++e) tmp[e] = tile[lc + e][oc];
    *(uint4*)(out + (size_t)(c0 + oc) * R + r0 + lc) = *(const uint4*)tmp;
  }
}

// ---------------- GEMM: C[M,N] = A(taps)[M,K] @ B[K,N] (+bias, relu) ----------------
template<int NTAPS, bool RELU>
__global__ __launch_bounds__(256)
void gemm_bt(const u16* __restrict__ A, const u16* __restrict__ BT,
             const float* __restrict__ bias, u16* __restrict__ C,
             int M, int N, int Korig, const u16* __restrict__ zp) {
  __shared__ __align__(16) u16 As[128 * 64];
  __shared__ __align__(16) u16 Bs[128 * 64];
  const int tid = threadIdx.x;
  const int m0 = blockIdx.y << 7;
  const int n0 = blockIdx.x << 7;
  const int Ktot = NTAPS * Korig;
  const int lane = tid & 63;
  const int w = tid >> 6;
  const int wm = (w >> 1) << 6;
  const int wn = (w & 1) << 6;
  const int fr = lane & 15;
  const int fko = (lane >> 4) << 3;
  const int srow = tid >> 3;          // 0..31
  const int scol = (tid & 7) << 3;    // 0..56

  f32x4 acc[4][4] = {};

  for (int k0 = 0; k0 < Ktot; k0 += 64) {
    int t = 0, c0 = k0;
    if (NTAPS == 3) { t = k0 / Korig; c0 = k0 - t * Korig; }
#pragma unroll
    for (int i = 0; i < 4; ++i) {
      const int row = srow + (i << 5);
      const u16* src;
      if (NTAPS == 3) {
        const int m = m0 + row;
        const int sp = (m & 1023) + t - 1;
        src = ((unsigned)sp < 1024u) ? (A + (size_t)(m + t - 1) * Korig + c0 + scol)
                                     : (zp + ((tid & 255) << 3));
      } else {
        src = A + (size_t)(m0 + row) * Korig + c0 + scol;
      }
      async16(src, &As[(row << 6) + scol]);
    }
#pragma unroll
    for (int i = 0; i < 4; ++i) {
      const int n = srow + (i << 5);
      async16(BT + (size_t)(n0 + n) * Ktot + k0 + scol, &Bs[(n << 6) + scol]);
    }
    asm volatile("s_waitcnt vmcnt(0)" ::: "memory");
    __syncthreads();
#pragma unroll
    for (int ks = 0; ks < 64; ks += 32) {
      bf16x8 af[4], bfr[4];
#pragma unroll
      for (int mi = 0; mi < 4; ++mi)
        af[mi] = *(const bf16x8*)&As[((wm + (mi << 4) + fr) << 6) + ks + fko];
#pragma unroll
      for (int ni = 0; ni < 4; ++ni)
        bfr[ni] = *(const bf16x8*)&Bs[((wn + (ni << 4) + fr) << 6) + ks + fko];
#pragma unroll
      for (int mi = 0; mi < 4; ++mi)
#pragma unroll
        for (int ni = 0; ni < 4; ++ni)
          acc[mi][ni] = __builtin_amdgcn_mfma_f32_16x16x32_bf16(af[mi], bfr[ni], acc[mi][ni], 0, 0, 0);
    }
    __syncthreads();
  }
  const int rbase = m0 + wm + ((lane >> 4) << 2);
  const int cbase = n0 + wn + fr;
#pragma unroll
  for (int ni = 0; ni < 4; ++ni) {
    const int col = cbase + (ni << 4);
    const float bv = bias ? bias[col] : 0.f;
#pragma unroll
    for (int mi = 0; mi < 4; ++mi) {
#pragma unroll
      for (int r = 0; r < 4; ++r) {
        float v = acc[mi][ni][r] + bv;
        if (RELU) v = fmaxf(v, 0.f);
        C[(size_t)(rbase + (mi << 4) + r) * N + col] = f2bf(v);
      }
    }
  }
}

// ---------------- V^T gather: Vt[(bm*1024+ch)][512] = V[b, padIdx[mb][j], ch] ----------------
__global__ __launch_bounds__(256)
void gather_v(const u16* __restrict__ qkv, const int* __restrict__ padIdx,
              const int* __restrict__ padCnt, u16* __restrict__ Vt) {
  const int bm = blockIdx.x;          // 16: b*4+mb
  const int jt = blockIdx.y;          // 8
  const int b = bm >> 2, mb = bm & 3;
  const int npad = padCnt[mb];
  const int npadR = (npad + 63) & ~63;
  if (jt * 64 >= npadR) return;
  const int tid = threadIdx.x;
  __shared__ int rows[64];
  if (tid < 64) {
    const int j = jt * 64 + tid;
    const int jj = j < npad ? j : npad - 1;
    rows[tid] = padIdx[(mb << 10) + jj];
  }
  __shared__ u16 tile[64][72];
  for (int c = 0; c < 16; ++c) {
    const int ch0 = c << 6;
    __syncthreads();
#pragma unroll
    for (int p = 0; p < 2; ++p) {
      const int r = (tid >> 3) + (p << 5);
      const int ch = (tid & 7) << 3;
      const uint4 v = *(const uint4*)(qkv + (size_t)((b << 10) + rows[r]) * 3072 + 2048 + ch0 + ch);
      const u16* us = (const u16*)&v;
#pragma unroll
      for (int e = 0; e < 8; ++e) tile[r][ch + e] = us[e];
    }
    __syncthreads();
#pragma unroll
    for (int p = 0; p < 2; ++p) {
      const int r = (tid >> 3) + (p << 5);   // channel row within chunk
      const int jc = (tid & 7) << 3;
      u16 tmp[8];
#pragma unroll
      for (int e = 0; e < 8; ++e) tmp[e] = tile[jc + e][r];
      *(uint4*)(Vt + (size_t)((bm << 10) + ch0 + r) * 512 + jt * 64 + jc) = *(const uint4*)tmp;
    }
  }
}

// ---------------- MFMA flash attention over PAD keys (faithful to mask bug) ----------------
// flat head i = b*16+h; mask batch = out batch = h&3; out head slot = i>>2
__global__ __launch_bounds__(256)
void attn_mfma(const u16* __restrict__ qkv, const u16* __restrict__ Vt,
               const int* __restrict__ padIdx, const int* __restrict__ padCnt,
               u16* __restrict__ vecS) {
  __shared__ __align__(16) u16 Ks[64 * 64];
  __shared__ __align__(16) u16 Vts[64 * 64];
  __shared__ __align__(16) u16 Ps[4][32 * 88];   // stride 88: 16B-aligned rows, ~2-way banks
  __shared__ int rowsIdx[512];
  const int i = blockIdx.x;     // 64
  const int qt = blockIdx.y;    // 8
  const int b = i >> 4, h = i & 15;
  const int mb = h & 3, bm = (b << 2) + mb;
  const int h_out = i >> 2;
  const int npad = padCnt[mb];
  const int nkt = (npad + 63) >> 6;
  const int tid = threadIdx.x;
  const int w = tid >> 6, lane = tid & 63;
  const int fr = lane & 15, quad = lane >> 4, fko = quad << 3;
  const int srow = tid >> 3, scol = (tid & 7) << 3;

  // stage clamped pad indices
#pragma unroll
  for (int p = 0; p < 2; ++p) {
    const int j = (p << 8) + tid;
    const int jj = j < npad ? j : npad - 1;
    rowsIdx[j] = padIdx[(mb << 10) + jj];
  }

  // Q A-fragments (held in registers for the whole block)
  const int qw = (qt << 7) + (w << 5);
  bf16x8 qf[2][2];
#pragma unroll
  for (int rt = 0; rt < 2; ++rt)
#pragma unroll
    for (int ks = 0; ks < 2; ++ks)
      qf[rt][ks] = *(const bf16x8*)(qkv + (size_t)((b << 10) + qw + (rt << 4) + fr) * 3072 +
                                    (h << 6) + (ks << 5) + fko);

  f32x4 O[2][4];
  float mrun[2][4], lrun[2][4];
#pragma unroll
  for (int rt = 0; rt < 2; ++rt)
#pragma unroll
    for (int r = 0; r < 4; ++r) {
      mrun[rt][r] = -1e30f; lrun[rt][r] = 0.f;
#pragma unroll
      for (int dt = 0; dt < 4; ++dt) O[rt][dt][r] = 0.f;
    }
  __syncthreads();   // rowsIdx visible

  for (int kt = 0; kt < nkt; ++kt) {
    // stage K (direct gather) and V^T tiles
#pragma unroll
    for (int p = 0; p < 2; ++p) {
      const int r = srow + (p << 5);
      const int grow = rowsIdx[(kt << 6) + r];
      async16(qkv + (size_t)((b << 10) + grow) * 3072 + 1024 + (h << 6) + scol,
              &Ks[(r << 6) + scol]);
      async16(Vt + (size_t)((bm << 10) + (h << 6) + r) * 512 + (kt << 6) + scol,
              &Vts[(r << 6) + scol]);
    }
    asm volatile("s_waitcnt vmcnt(0)" ::: "memory");
    __syncthreads();

    // S = Q @ K^T
    f32x4 S[2][4];
#pragma unroll
    for (int rt = 0; rt < 2; ++rt)
#pragma unroll
      for (int nt = 0; nt < 4; ++nt)
#pragma unroll
        for (int r = 0; r < 4; ++r) S[rt][nt][r] = 0.f;
#pragma unroll
    for (int ks = 0; ks < 2; ++ks) {
      bf16x8 bfr[4];
#pragma unroll
      for (int nt = 0; nt < 4; ++nt)
        bfr[nt] = *(const bf16x8*)&Ks[(((nt << 4) + fr) << 6) + (ks << 5) + fko];
#pragma unroll
      for (int rt = 0; rt < 2; ++rt)
#pragma unroll
        for (int nt = 0; nt < 4; ++nt)
          S[rt][nt] = __builtin_amdgcn_mfma_f32_16x16x32_bf16(qf[rt][ks], bfr[nt], S[rt][nt], 0, 0, 0);
    }

    // scale + tail mask
#pragma unroll
    for (int nt = 0; nt < 4; ++nt) {
      const int key = (kt << 6) + (nt << 4) + fr;
      const bool dead = (key >= npad);
#pragma unroll
      for (int rt = 0; rt < 2; ++rt)
#pragma unroll
        for (int r = 0; r < 4; ++r) {
          float s = S[rt][nt][r] * 0.125f;
          S[rt][nt][r] = dead ? -1e30f : s;
        }
    }

    // online softmax per q-row (rows live in quad; cols in lane&15)
#pragma unroll
    for (int rt = 0; rt < 2; ++rt) {
#pragma unroll
      for (int r = 0; r < 4; ++r) {
        float mx = fmaxf(fmaxf(S[rt][0][r], S[rt][1][r]), fmaxf(S[rt][2][r], S[rt][3][r]));
#pragma unroll
        for (int off = 1; off <= 8; off <<= 1) mx = fmaxf(mx, __shfl_xor(mx, off, 64));
        const float mnew = fmaxf(mrun[rt][r], mx);
        const float alpha = __expf(mrun[rt][r] - mnew);
        mrun[rt][r] = mnew;
        float rsum = 0.f;
#pragma unroll
        for (int nt = 0; nt < 4; ++nt) {
          const float p_ = __expf(S[rt][nt][r] - mnew);
          S[rt][nt][r] = p_;
          rsum += p_;
        }
#pragma unroll
        for (int off = 1; off <= 8; off <<= 1) rsum += __shfl_xor(rsum, off, 64);
        lrun[rt][r] = lrun[rt][r] * alpha + rsum;
#pragma unroll
        for (int dt = 0; dt < 4; ++dt) O[rt][dt][r] *= alpha;
      }
    }

    // P -> wave-private LDS (C-layout -> A-layout transpose)
    u16* ps = &Ps[w][0];
#pragma unroll
    for (int rt = 0; rt < 2; ++rt)
#pragma unroll
      for (int nt = 0; nt < 4; ++nt)
#pragma unroll
        for (int r = 0; r < 4; ++r)
          ps[((rt << 4) + (quad << 2) + r) * 88 + (nt << 4) + fr] = f2bf(S[rt][nt][r]);
    asm volatile("s_waitcnt lgkmcnt(0)" ::: "memory");

    // O += P @ V
#pragma unroll
    for (int ks = 0; ks < 2; ++ks) {
      bf16x8 af[2], bv[4];
#pragma unroll
      for (int rt = 0; rt < 2; ++rt)
        af[rt] = *(const bf16x8*)&ps[((rt << 4) + fr) * 88 + (ks << 5) + fko];
#pragma unroll
      for (int dt = 0; dt < 4; ++dt)
        bv[dt] = *(const bf16x8*)&Vts[(((dt << 4) + fr) << 6) + (ks << 5) + fko];
#pragma unroll
      for (int rt = 0; rt < 2; ++rt)
#pragma unroll
        for (int dt = 0; dt < 4; ++dt)
          O[rt][dt] = __builtin_amdgcn_mfma_f32_16x16x32_bf16(af[rt], bv[dt], O[rt][dt], 0, 0, 0);
    }
    __syncthreads();   // protect Ks/Vts before next staging
  }

  // epilogue: normalize + scrambled write
#pragma unroll
  for (int rt = 0; rt < 2; ++rt)
#pragma unroll
    for (int r = 0; r < 4; ++r) {
      const float inv = 1.f / lrun[rt][r];
      const int q = qw + (rt << 4) + (quad << 2) + r;
      u16* orow = vecS + (size_t)((mb << 10) + q) * 1024 + (h_out << 6);
#pragma unroll
      for (int dt = 0; dt < 4; ++dt)
        orow[(dt << 4) + fr] = f2bf(O[rt][dt][r] * inv);
    }
}

// ---------------- residual + layernorm + mask-mul ----------------
template<bool XF32, bool OUTF32>
__global__ __launch_bounds__(256)
void ln_kernel(const void* __restrict__ Xv, const u16* __restrict__ Yd,
               const float* __restrict__ g, const float* __restrict__ be,
               const float* __restrict__ maskf, void* __restrict__ outv) {
  const int r = blockIdx.x;
  const int tid = threadIdx.x;
  const size_t base = (size_t)r << 10;
  const float* Xf = (const float*)Xv;
  const u16* Xb = (const u16*)Xv;
  float x[4];
  float s1 = 0.f, s2 = 0.f;
#pragma unroll
  for (int j = 0; j < 4; ++j) {
    const int c = (tid << 2) + j;
    const float xv = XF32 ? Xf[base + c] : bf2f(Xb[base + c]);
    const float v = xv + bf2f(Yd[base + c]);
    x[j] = v; s1 += v; s2 += v * v;
  }
#pragma unroll
  for (int off = 32; off > 0; off >>= 1) { s1 += __shfl_xor(s1, off, 64); s2 += __shfl_xor(s2, off, 64); }
  __shared__ float rs1[4], rs2[4];
  if ((tid & 63) == 0) { rs1[tid >> 6] = s1; rs2[tid >> 6] = s2; }
  __syncthreads();
  s1 = rs1[0] + rs1[1] + rs1[2] + rs1[3];
  s2 = rs2[0] + rs2[1] + rs2[2] + rs2[3];
  const float mean = s1 * (1.f / 1024.f);
  const float var = s2 * (1.f / 1024.f) - mean * mean;
  const float rstd = rsqrtf(var + 1e-3f);
  const float mv = maskf[r];
#pragma unroll
  for (int j = 0; j < 4; ++j) {
    const int c = (tid << 2) + j;
    const float y = ((x[j] - mean) * rstd * g[c] + be[c]) * mv;
    if (OUTF32) ((float*)outv)[base + c] = y;
    else ((u16*)outv)[base + c] = f2bf(y);
  }
}

extern "C" void kernel_launch(void* const* d_in, const int* in_sizes, int n_in,
                              void* d_out, int out_size, void* d_ws, size_t ws_size,
                              hipStream_t stream) {
  (void)in_sizes; (void)n_in; (void)out_size; (void)ws_size;
  const float* dec  = (const float*)d_in[0];
  const unsigned char* mask = (const unsigned char*)d_in[1];
  const float* wqkv = (const float*)d_in[2];
  const float* bqkv = (const float*)d_in[3];
  const float* wo   = (const float*)d_in[4];
  const float* g1   = (const float*)d_in[5];
  const float* b1   = (const float*)d_in[6];
  const float* w1   = (const float*)d_in[7];
  const float* bc1  = (const float*)d_in[8];
  const float* w2   = (const float*)d_in[9];
  const float* bc2  = (const float*)d_in[10];
  const float* g2   = (const float*)d_in[11];
  const float* b2   = (const float*)d_in[12];
  char* ws = (char*)d_ws;
  // workspace layout (bytes), repacked by lifetime — peak 117,506,048 (same as proven)
  u16*   zp    = (u16*)(ws + 0);            // 4 KB zero page
  int*   pcnt  = (int*)(ws + 4096);
  float* maskf = (float*)(ws + 8192);       // [4096]
  int*   pidx  = (int*)(ws + 24576);        // [4][1024]
  u16*   decB  = (u16*)(ws + 65536);        // [4096][1024]   ends 8454144   (dead after QKV gemm)
  u16*   wqkvT = (u16*)(ws + 8454144);      // [3072][1024]   ends 14745600  (dead after QKV gemm)
  u16*   woT   = (u16*)(ws + 14745600);     // [1024][1024]   ends 16842752  (dead after atto gemm)
  u16*   w1T   = (u16*)(ws + 16842752);     // [4096][3072]   ends 42008576
  u16*   w2T   = (u16*)(ws + 42008576);     // [1024][12288]  ends 67174400
  u16*   qkv   = (u16*)(ws + 67174400);     // [4096][3072]   ends 92340224  (dead after attn)
  u16*   Vt    = (u16*)(ws + 92340224);     // [16*1024][512] ends 109117440 (dead after attn)
  u16*   vecS  = (u16*)(ws + 109117440);    // [4096][1024]   ends 117506048 (dead after atto gemm)
  u16*   atto  = (u16*)(ws + 65536);        // reuses decB region
  u16*   x1bf  = (u16*)(ws + 8454144);      // reuses wqkvT+woT region
  u16*   ybuf  = (u16*)(ws + 67174400);     // [4096][4096] reuses qkv+Vt
  u16*   core  = (u16*)(ws + 109117440);    // reuses vecS region

  hipMemsetAsync(zp, 0, 4096, stream);
  compact_mask<<<dim3(4), dim3(64), 0, stream>>>(mask, pidx, pcnt, maskf);
  f32_to_bf16<<<dim3(4096), dim3(256), 0, stream>>>(dec, decB, 1048576);
  transpose_f32_bf16<<<dim3(48, 16), dim3(256), 0, stream>>>(wqkv, wqkvT, 1024, 3072);
  transpose_f32_bf16<<<dim3(16, 16), dim3(256), 0, stream>>>(wo, woT, 1024, 1024);
  transpose_f32_bf16<<<dim3(64, 48), dim3(256), 0, stream>>>(w1, w1T, 3072, 4096);
  transpose_f32_bf16<<<dim3(16, 192), dim3(256), 0, stream>>>(w2, w2T, 12288, 1024);
  // qkv = dec @ qkv_w + qkv_b
  gemm_bt<1, false><<<dim3(24, 32), dim3(256), 0, stream>>>(decB, wqkvT, bqkv, qkv, 4096, 3072, 1024, zp);
  // attention (pad-keys-only MFMA flash, scrambled output)
  gather_v<<<dim3(16, 8), dim3(256), 0, stream>>>(qkv, pidx, pcnt, Vt);
  attn_mfma<<<dim3(64, 8), dim3(256), 0, stream>>>(qkv, Vt, pidx, pcnt, vecS);
  // attn_out = vecS @ o_w
  gemm_bt<1, false><<<dim3(8, 32), dim3(256), 0, stream>>>(vecS, woT, nullptr, atto, 4096, 1024, 1024, zp);
  // x1 = LN1(dec + attn_out) * mask
  ln_kernel<true, false><<<dim3(4096), dim3(256), 0, stream>>>(dec, atto, g1, b1, maskf, x1bf);
  // y = relu(conv1(x1))
  gemm_bt<3, true><<<dim3(32, 32), dim3(256), 0, stream>>>(x1bf, w1T, bc1, ybuf, 4096, 4096, 1024, zp);
  // core = conv2(y)
  gemm_bt<3, false><<<dim3(8, 32), dim3(256), 0, stream>>>(ybuf, w2T, bc2, core, 4096, 1024, 4096, zp);
  // out = LN2(x1 + core) * mask  -> fp32 d_out
  ln_kernel<false, true><<<dim3(4096), dim3(256), 0, stream>>>(x1bf, core, g2, b2, maskf, (float*)d_out);
}

// Round 4
// 585.554 us; speedup vs baseline: 1.9497x; 1.3146x over previous
//
#include <hip/hip_runtime.h>
#include <cstdint>
#include <cstddef>

typedef float f32x4 __attribute__((ext_vector_type(4)));
typedef __bf16 bf16x8 __attribute__((ext_vector_type(8)));
typedef unsigned short u16;

__device__ __forceinline__ float bf2f(u16 u) {
  union { unsigned int i; float f; } x; x.i = ((unsigned int)u) << 16; return x.f;
}
__device__ __forceinline__ u16 f2bf(float f) {
  union { float f; unsigned int i; } x; x.f = f;
  unsigned int i = x.i;
  i += 0x7fffu + ((i >> 16) & 1u);   // round-to-nearest-even
  return (u16)(i >> 16);
}

#if defined(__has_builtin)
#if __has_builtin(__builtin_amdgcn_global_load_lds)
#define HAS_GLL 1
#endif
#endif

__device__ __forceinline__ void async16(const u16* g, u16* l) {
#ifdef HAS_GLL
  __builtin_amdgcn_global_load_lds((const __attribute__((address_space(1))) void*)(const void*)g,
                                   (__attribute__((address_space(3))) void*)(void*)l, 16, 0, 0);
#else
  *(uint4*)l = *(const uint4*)g;
#endif
}

// ---------------- mask compaction (dtype-width-agnostic) ----------------
__global__ void compact_mask(const unsigned char* __restrict__ mask,
                             int* __restrict__ padIdx, int* __restrict__ padCnt,
                             float* __restrict__ maskf) {
  const int b = blockIdx.x;        // 4 rows
  const int lane = threadIdx.x;    // 64
  int stride = 1;
  if (mask[1] == 0) stride = (mask[4] != 0) ? 4 : 8;
  int cnt = 0;
  for (int s0 = 0; s0 < 1024; s0 += 64) {
    const int s = s0 + lane;
    const bool valid = (mask[(size_t)((b << 10) + s) * stride] != 0);
    maskf[(b << 10) + s] = valid ? 1.f : 0.f;
    const bool pad = !valid;
    const unsigned long long bal = __ballot(pad);
    const int rank = (int)__popcll(bal & ((1ull << lane) - 1ull));
    if (pad) padIdx[(b << 10) + cnt + rank] = s;
    cnt += (int)__popcll(bal);
  }
  if (lane == 0) padCnt[b] = cnt;
}

// ---------------- fp32 -> bf16 convert ----------------
__global__ __launch_bounds__(256)
void f32_to_bf16(const float* __restrict__ in, u16* __restrict__ out, int n4) {
  const int i = blockIdx.x * 256 + threadIdx.x;
  if (i < n4) {
    const float4 v = ((const float4*)in)[i];
    u16 o[4] = { f2bf(v.x), f2bf(v.y), f2bf(v.z), f2bf(v.w) };
    ((ushort4*)out)[i] = *(const ushort4*)o;
  }
}

// ---------------- fp32 transpose+convert: in[R][C] f32 -> out[C][R] bf16 ----------------
__global__ __launch_bounds__(256)
void transpose_f32_bf16(const float* __restrict__ in, u16* __restrict__ out, int R, int C) {
  __shared__ u16 tile[64][65];
  const int r0 = blockIdx.y << 6, c0 = blockIdx.x << 6;
  const int tid = threadIdx.x;
  const int lr = tid >> 3, lc = (tid & 7) << 3;
#pragma unroll
  for (int p = 0; p < 2; ++p) {
    const int row = lr + (p << 5);
    const float4 a = *(const float4*)(in + (size_t)(r0 + row) * C + c0 + lc);
    const float4 bq = *(const float4*)(in + (size_t)(r0 + row) * C + c0 + lc + 4);
    tile[row][lc + 0] = f2bf(a.x); tile[row][lc + 1] = f2bf(a.y);
    tile[row][lc + 2] = f2bf(a.z); tile[row][lc + 3] = f2bf(a.w);
    tile[row][lc + 4] = f2bf(bq.x); tile[row][lc + 5] = f2bf(bq.y);
    tile[row][lc + 6] = f2bf(bq.z); tile[row][lc + 7] = f2bf(bq.w);
  }
  __syncthreads();
#pragma unroll
  for (int p = 0; p < 2; ++p) {
    const int oc = lr + (p << 5);
    u16 tmp[8];
#pragma unroll
    for (int e = 0; e < 8; ++e) tmp[e] = tile[lc + e][oc];
    *(uint4*)(out + (size_t)(c0 + oc) * R + r0 + lc) = *(const uint4*)tmp;
  }
}

// ---------------- GEMM: C[M,N] = A(taps)[M,K] @ B[K,N] (+bias, relu) ----------------
// LDS layout is column-block-swizzled: cell (row, c8) holds global col-block c8^(row&7).
// SPLITK>1: blockIdx.z selects K-chunk; raw bf16 partial -> P0 (kz=0) / P1+(kz-1)*MN.
template<int NTAPS, bool RELU, int SPLITK>
__global__ __launch_bounds__(256)
void gemm_bt(const u16* __restrict__ A, const u16* __restrict__ BT,
             const float* __restrict__ bias, u16* __restrict__ C, u16* __restrict__ Calt,
             int M, int N, int Korig, const u16* __restrict__ zp) {
  __shared__ __align__(16) u16 As[128 * 64];
  __shared__ __align__(16) u16 Bs[128 * 64];
  const int tid = threadIdx.x;
  const int m0 = blockIdx.y << 7;
  const int n0 = blockIdx.x << 7;
  const int kz = (SPLITK > 1) ? blockIdx.z : 0;
  const int Ktot = NTAPS * Korig;
  const int kchunk = Ktot / SPLITK;
  const int lane = tid & 63;
  const int w = tid >> 6;
  const int wm = (w >> 1) << 6;
  const int wn = (w & 1) << 6;
  const int fr = lane & 15;
  const int quad = lane >> 4;
  const int srow = tid >> 3;          // 0..31
  const int scol = (tid & 7) << 3;    // LDS dest col (fixed: lane*16B)
  const int sx = (((tid & 7) ^ (srow & 7)) << 3);   // swizzled source col

  f32x4 acc[4][4] = {};

  const int kbeg = kz * kchunk, kend = kbeg + kchunk;
  for (int k0 = kbeg; k0 < kend; k0 += 64) {
    int t = 0, c0 = k0;
    if (NTAPS == 3) { t = k0 / Korig; c0 = k0 - t * Korig; }
#pragma unroll
    for (int i = 0; i < 4; ++i) {
      const int row = srow + (i << 5);
      const u16* src;
      if (NTAPS == 3) {
        const int m = m0 + row;
        const int sp = (m & 1023) + t - 1;
        src = ((unsigned)sp < 1024u) ? (A + (size_t)(m + t - 1) * Korig + c0 + sx)
                                     : (zp + ((tid & 255) << 3));
      } else {
        src = A + (size_t)(m0 + row) * Korig + c0 + sx;
      }
      async16(src, &As[(row << 6) + scol]);
    }
#pragma unroll
    for (int i = 0; i < 4; ++i) {
      const int n = srow + (i << 5);
      async16(BT + (size_t)(n0 + n) * Ktot + k0 + sx, &Bs[(n << 6) + scol]);
    }
    asm volatile("s_waitcnt vmcnt(0)" ::: "memory");
    __syncthreads();
#pragma unroll
    for (int ks = 0; ks < 64; ks += 32) {
      const int ccol = ((((ks >> 3) + quad) ^ (fr & 7)) << 3);
      bf16x8 af[4], bfr[4];
#pragma unroll
      for (int mi = 0; mi < 4; ++mi)
        af[mi] = *(const bf16x8*)&As[((wm + (mi << 4) + fr) << 6) + ccol];
#pragma unroll
      for (int ni = 0; ni < 4; ++ni)
        bfr[ni] = *(const bf16x8*)&Bs[((wn + (ni << 4) + fr) << 6) + ccol];
#pragma unroll
      for (int mi = 0; mi < 4; ++mi)
#pragma unroll
        for (int ni = 0; ni < 4; ++ni)
          acc[mi][ni] = __builtin_amdgcn_mfma_f32_16x16x32_bf16(af[mi], bfr[ni], acc[mi][ni], 0, 0, 0);
    }
    __syncthreads();
  }
  const int rbase = m0 + wm + (quad << 2);
  const int cbase = n0 + wn + fr;
  u16* dst = C;
  if (SPLITK > 1 && kz > 0) dst = Calt + (size_t)(kz - 1) * ((size_t)M * N);
#pragma unroll
  for (int ni = 0; ni < 4; ++ni) {
    const int col = cbase + (ni << 4);
    const float bv = (SPLITK == 1 && bias) ? bias[col] : 0.f;
#pragma unroll
    for (int mi = 0; mi < 4; ++mi) {
#pragma unroll
      for (int r = 0; r < 4; ++r) {
        float v = acc[mi][ni][r] + bv;
        if (RELU) v = fmaxf(v, 0.f);
        dst[(size_t)(rbase + (mi << 4) + r) * N + col] = f2bf(v);
      }
    }
  }
}

// ---------------- split-K reduce: out = P0 + P1[0..2] + bias ----------------
__global__ __launch_bounds__(256)
void reduce_split4(const u16* __restrict__ P0, const u16* __restrict__ P1,
                   const float* __restrict__ bias, u16* __restrict__ out,
                   int MN, int Ncols) {
  const int i8 = (blockIdx.x * 256 + threadIdx.x) << 3;
  if (i8 >= MN) return;
  const uint4 a = *(const uint4*)(P0 + i8);
  const uint4 b = *(const uint4*)(P1 + i8);
  const uint4 c = *(const uint4*)(P1 + MN + i8);
  const uint4 d = *(const uint4*)(P1 + 2 * MN + i8);
  const u16 *ua = (const u16*)&a, *ub = (const u16*)&b, *uc = (const u16*)&c, *ud = (const u16*)&d;
  const int cb = i8 & (Ncols - 1);
  u16 o[8];
#pragma unroll
  for (int e = 0; e < 8; ++e) {
    const float s = bf2f(ua[e]) + bf2f(ub[e]) + bf2f(uc[e]) + bf2f(ud[e]) + bias[cb + e];
    o[e] = f2bf(s);
  }
  *(uint4*)(out + i8) = *(const uint4*)o;
}

// ---------------- V^T gather: Vt[(bm*1024+ch)][512] = V[b, padIdx[mb][j], ch] ----------------
__global__ __launch_bounds__(256)
void gather_v(const u16* __restrict__ qkv, const int* __restrict__ padIdx,
              const int* __restrict__ padCnt, u16* __restrict__ Vt) {
  const int bm = blockIdx.x;          // 16: b*4+mb
  const int jt = blockIdx.y;          // 8
  const int b = bm >> 2, mb = bm & 3;
  const int npad = padCnt[mb];
  const int npadR = (npad + 63) & ~63;
  if (jt * 64 >= npadR) return;
  const int tid = threadIdx.x;
  __shared__ int rows[64];
  if (tid < 64) {
    const int j = jt * 64 + tid;
    const int jj = j < npad ? j : npad - 1;
    rows[tid] = padIdx[(mb << 10) + jj];
  }
  __shared__ u16 tile[64][72];
  for (int c = 0; c < 16; ++c) {
    const int ch0 = c << 6;
    __syncthreads();
#pragma unroll
    for (int p = 0; p < 2; ++p) {
      const int r = (tid >> 3) + (p << 5);
      const int ch = (tid & 7) << 3;
      const uint4 v = *(const uint4*)(qkv + (size_t)((b << 10) + rows[r]) * 3072 + 2048 + ch0 + ch);
      const u16* us = (const u16*)&v;
#pragma unroll
      for (int e = 0; e < 8; ++e) tile[r][ch + e] = us[e];
    }
    __syncthreads();
#pragma unroll
    for (int p = 0; p < 2; ++p) {
      const int r = (tid >> 3) + (p << 5);   // channel row within chunk
      const int jc = (tid & 7) << 3;
      u16 tmp[8];
#pragma unroll
      for (int e = 0; e < 8; ++e) tmp[e] = tile[jc + e][r];
      *(uint4*)(Vt + (size_t)((bm << 10) + ch0 + r) * 512 + jt * 64 + jc) = *(const uint4*)tmp;
    }
  }
}

// ---------------- MFMA flash attention over PAD keys (faithful to mask bug) ----------------
// flat head i = b*16+h; mask batch = out batch = h&3; out head slot = i>>2
// Ks/Vts use the same col-block swizzle as gemm_bt.
__global__ __launch_bounds__(256)
void attn_mfma(const u16* __restrict__ qkv, const u16* __restrict__ Vt,
               const int* __restrict__ padIdx, const int* __restrict__ padCnt,
               u16* __restrict__ vecS) {
  __shared__ __align__(16) u16 Ks[64 * 64];
  __shared__ __align__(16) u16 Vts[64 * 64];
  __shared__ __align__(16) u16 Ps[4][32 * 88];   // stride 88: 16B-aligned rows
  __shared__ int rowsIdx[512];
  const int i = blockIdx.x;     // 64
  const int qt = blockIdx.y;    // 8
  const int b = i >> 4, h = i & 15;
  const int mb = h & 3, bm = (b << 2) + mb;
  const int h_out = i >> 2;
  const int npad = padCnt[mb];
  const int nkt = (npad + 63) >> 6;
  const int tid = threadIdx.x;
  const int w = tid >> 6, lane = tid & 63;
  const int fr = lane & 15, quad = lane >> 4, fko = quad << 3;
  const int srow = tid >> 3, scol = (tid & 7) << 3;
  const int sx = (((tid & 7) ^ (srow & 7)) << 3);   // swizzled source col

  // stage clamped pad indices
#pragma unroll
  for (int p = 0; p < 2; ++p) {
    const int j = (p << 8) + tid;
    const int jj = j < npad ? j : npad - 1;
    rowsIdx[j] = padIdx[(mb << 10) + jj];
  }

  // Q A-fragments (registers for the whole block)
  const int qw = (qt << 7) + (w << 5);
  bf16x8 qf[2][2];
#pragma unroll
  for (int rt = 0; rt < 2; ++rt)
#pragma unroll
    for (int ks = 0; ks < 2; ++ks)
      qf[rt][ks] = *(const bf16x8*)(qkv + (size_t)((b << 10) + qw + (rt << 4) + fr) * 3072 +
                                    (h << 6) + (ks << 5) + fko);

  f32x4 O[2][4];
  float mrun[2][4], lrun[2][4];
#pragma unroll
  for (int rt = 0; rt < 2; ++rt)
#pragma unroll
    for (int r = 0; r < 4; ++r) {
      mrun[rt][r] = -1e30f; lrun[rt][r] = 0.f;
#pragma unroll
      for (int dt = 0; dt < 4; ++dt) O[rt][dt][r] = 0.f;
    }
  __syncthreads();   // rowsIdx visible

  for (int kt = 0; kt < nkt; ++kt) {
    // stage K (direct swizzled gather) and V^T tiles
#pragma unroll
    for (int p = 0; p < 2; ++p) {
      const int r = srow + (p << 5);
      const int grow = rowsIdx[(kt << 6) + r];
      async16(qkv + (size_t)((b << 10) + grow) * 3072 + 1024 + (h << 6) + sx,
              &Ks[(r << 6) + scol]);
      async16(Vt + (size_t)((bm << 10) + (h << 6) + r) * 512 + (kt << 6) + sx,
              &Vts[(r << 6) + scol]);
    }
    asm volatile("s_waitcnt vmcnt(0)" ::: "memory");
    __syncthreads();

    // S = Q @ K^T
    f32x4 S[2][4];
#pragma unroll
    for (int rt = 0; rt < 2; ++rt)
#pragma unroll
      for (int nt = 0; nt < 4; ++nt)
#pragma unroll
        for (int r = 0; r < 4; ++r) S[rt][nt][r] = 0.f;
#pragma unroll
    for (int ks = 0; ks < 2; ++ks) {
      const int ccol = ((((ks << 2) + quad) ^ (fr & 7)) << 3);
      bf16x8 bfr[4];
#pragma unroll
      for (int nt = 0; nt < 4; ++nt)
        bfr[nt] = *(const bf16x8*)&Ks[(((nt << 4) + fr) << 6) + ccol];
#pragma unroll
      for (int rt = 0; rt < 2; ++rt)
#pragma unroll
        for (int nt = 0; nt < 4; ++nt)
          S[rt][nt] = __builtin_amdgcn_mfma_f32_16x16x32_bf16(qf[rt][ks], bfr[nt], S[rt][nt], 0, 0, 0);
    }

    // scale + tail mask
#pragma unroll
    for (int nt = 0; nt < 4; ++nt) {
      const int key = (kt << 6) + (nt << 4) + fr;
      const bool dead = (key >= npad);
#pragma unroll
      for (int rt = 0; rt < 2; ++rt)
#pragma unroll
        for (int r = 0; r < 4; ++r) {
          float s = S[rt][nt][r] * 0.125f;
          S[rt][nt][r] = dead ? -1e30f : s;
        }
    }

    // online softmax per q-row (rows live in quad; cols in lane&15)
#pragma unroll
    for (int rt = 0; rt < 2; ++rt) {
#pragma unroll
      for (int r = 0; r < 4; ++r) {
        float mx = fmaxf(fmaxf(S[rt][0][r], S[rt][1][r]), fmaxf(S[rt][2][r], S[rt][3][r]));
#pragma unroll
        for (int off = 1; off <= 8; off <<= 1) mx = fmaxf(mx, __shfl_xor(mx, off, 64));
        const float mnew = fmaxf(mrun[rt][r], mx);
        const float alpha = __expf(mrun[rt][r] - mnew);
        mrun[rt][r] = mnew;
        float rsum = 0.f;
#pragma unroll
        for (int nt = 0; nt < 4; ++nt) {
          const float p_ = __expf(S[rt][nt][r] - mnew);
          S[rt][nt][r] = p_;
          rsum += p_;
        }
#pragma unroll
        for (int off = 1; off <= 8; off <<= 1) rsum += __shfl_xor(rsum, off, 64);
        lrun[rt][r] = lrun[rt][r] * alpha + rsum;
#pragma unroll
        for (int dt = 0; dt < 4; ++dt) O[rt][dt][r] *= alpha;
      }
    }

    // P -> wave-private LDS (C-layout -> A-layout transpose)
    u16* ps = &Ps[w][0];
#pragma unroll
    for (int rt = 0; rt < 2; ++rt)
#pragma unroll
      for (int nt = 0; nt < 4; ++nt)
#pragma unroll
        for (int r = 0; r < 4; ++r)
          ps[((rt << 4) + (quad << 2) + r) * 88 + (nt << 4) + fr] = f2bf(S[rt][nt][r]);
    asm volatile("s_waitcnt lgkmcnt(0)" ::: "memory");

    // O += P @ V
#pragma unroll
    for (int ks = 0; ks < 2; ++ks) {
      const int ccol = ((((ks << 2) + quad) ^ (fr & 7)) << 3);
      bf16x8 af[2], bv[4];
#pragma unroll
      for (int rt = 0; rt < 2; ++rt)
        af[rt] = *(const bf16x8*)&ps[((rt << 4) + fr) * 88 + (ks << 5) + fko];
#pragma unroll
      for (int dt = 0; dt < 4; ++dt)
        bv[dt] = *(const bf16x8*)&Vts[(((dt << 4) + fr) << 6) + ccol];
#pragma unroll
      for (int rt = 0; rt < 2; ++rt)
#pragma unroll
        for (int dt = 0; dt < 4; ++dt)
          O[rt][dt] = __builtin_amdgcn_mfma_f32_16x16x32_bf16(af[rt], bv[dt], O[rt][dt], 0, 0, 0);
    }
    __syncthreads();   // protect Ks/Vts before next staging
  }

  // epilogue: normalize + scrambled write
#pragma unroll
  for (int rt = 0; rt < 2; ++rt)
#pragma unroll
    for (int r = 0; r < 4; ++r) {
      const float inv = 1.f / lrun[rt][r];
      const int q = qw + (rt << 4) + (quad << 2) + r;
      u16* orow = vecS + (size_t)((mb << 10) + q) * 1024 + (h_out << 6);
#pragma unroll
      for (int dt = 0; dt < 4; ++dt)
        orow[(dt << 4) + fr] = f2bf(O[rt][dt][r] * inv);
    }
}

// ---------------- residual + layernorm + mask-mul ----------------
template<bool XF32, bool OUTF32>
__global__ __launch_bounds__(256)
void ln_kernel(const void* __restrict__ Xv, const u16* __restrict__ Yd,
               const float* __restrict__ g, const float* __restrict__ be,
               const float* __restrict__ maskf, void* __restrict__ outv) {
  const int r = blockIdx.x;
  const int tid = threadIdx.x;
  const size_t base = (size_t)r << 10;
  const float* Xf = (const float*)Xv;
  const u16* Xb = (const u16*)Xv;
  float x[4];
  float s1 = 0.f, s2 = 0.f;
#pragma unroll
  for (int j = 0; j < 4; ++j) {
    const int c = (tid << 2) + j;
    const float xv = XF32 ? Xf[base + c] : bf2f(Xb[base + c]);
    const float v = xv + bf2f(Yd[base + c]);
    x[j] = v; s1 += v; s2 += v * v;
  }
#pragma unroll
  for (int off = 32; off > 0; off >>= 1) { s1 += __shfl_xor(s1, off, 64); s2 += __shfl_xor(s2, off, 64); }
  __shared__ float rs1[4], rs2[4];
  if ((tid & 63) == 0) { rs1[tid >> 6] = s1; rs2[tid >> 6] = s2; }
  __syncthreads();
  s1 = rs1[0] + rs1[1] + rs1[2] + rs1[3];
  s2 = rs2[0] + rs2[1] + rs2[2] + rs2[3];
  const float mean = s1 * (1.f / 1024.f);
  const float var = s2 * (1.f / 1024.f) - mean * mean;
  const float rstd = rsqrtf(var + 1e-3f);
  const float mv = maskf[r];
#pragma unroll
  for (int j = 0; j < 4; ++j) {
    const int c = (tid << 2) + j;
    const float y = ((x[j] - mean) * rstd * g[c] + be[c]) * mv;
    if (OUTF32) ((float*)outv)[base + c] = y;
    else ((u16*)outv)[base + c] = f2bf(y);
  }
}

extern "C" void kernel_launch(void* const* d_in, const int* in_sizes, int n_in,
                              void* d_out, int out_size, void* d_ws, size_t ws_size,
                              hipStream_t stream) {
  (void)in_sizes; (void)n_in; (void)out_size; (void)ws_size;
  const float* dec  = (const float*)d_in[0];
  const unsigned char* mask = (const unsigned char*)d_in[1];
  const float* wqkv = (const float*)d_in[2];
  const float* bqkv = (const float*)d_in[3];
  const float* wo   = (const float*)d_in[4];
  const float* g1   = (const float*)d_in[5];
  const float* b1   = (const float*)d_in[6];
  const float* w1   = (const float*)d_in[7];
  const float* bc1  = (const float*)d_in[8];
  const float* w2   = (const float*)d_in[9];
  const float* bc2  = (const float*)d_in[10];
  const float* g2   = (const float*)d_in[11];
  const float* b2   = (const float*)d_in[12];
  char* ws = (char*)d_ws;
  // workspace layout (bytes), peak 117,506,048 (same as proven)
  u16*   zp    = (u16*)(ws + 0);            // 4 KB zero page
  int*   pcnt  = (int*)(ws + 4096);
  float* maskf = (float*)(ws + 8192);       // [4096]
  int*   pidx  = (int*)(ws + 24576);        // [4][1024]
  u16*   decB  = (u16*)(ws + 65536);        // [4096][1024]   ends 8454144   (dead after QKV gemm)
  u16*   wqkvT = (u16*)(ws + 8454144);      // [3072][1024]   ends 14745600  (dead after QKV gemm)
  u16*   woT   = (u16*)(ws + 14745600);     // [1024][1024]   ends 16842752  (dead after atto gemm)
  u16*   w1T   = (u16*)(ws + 16842752);     // [4096][3072]   ends 42008576  (dead after conv1)
  u16*   w2T   = (u16*)(ws + 42008576);     // [1024][12288]  ends 67174400
  u16*   qkv   = (u16*)(ws + 67174400);     // [4096][3072]   ends 92340224  (dead after attn)
  u16*   Vt    = (u16*)(ws + 92340224);     // [16*1024][512] ends 109117440 (dead after attn)
  u16*   vecS  = (u16*)(ws + 109117440);    // [4096][1024]   ends 117506048 (dead after atto gemm)
  u16*   atto  = (u16*)(ws + 65536);        // reuses decB region (dead after LN1)
  u16*   x1bf  = (u16*)(ws + 8454144);      // reuses wqkvT+woT region
  u16*   ybuf  = (u16*)(ws + 67174400);     // [4096][4096] reuses qkv+Vt
  u16*   core  = (u16*)(ws + 109117440);    // reuses vecS region
  u16*   P0    = (u16*)(ws + 65536);        // split-K partial kz=0: 8,388,608 B (decB/atto region)
  u16*   P1    = (u16*)(ws + 16842752);     // split-K partials kz=1..3: 3 x 8,388,608 B (w1T region)

  hipMemsetAsync(zp, 0, 4096, stream);
  compact_mask<<<dim3(4), dim3(64), 0, stream>>>(mask, pidx, pcnt, maskf);
  f32_to_bf16<<<dim3(4096), dim3(256), 0, stream>>>(dec, decB, 1048576);
  transpose_f32_bf16<<<dim3(48, 16), dim3(256), 0, stream>>>(wqkv, wqkvT, 1024, 3072);
  transpose_f32_bf16<<<dim3(16, 16), dim3(256), 0, stream>>>(wo, woT, 1024, 1024);
  transpose_f32_bf16<<<dim3(64, 48), dim3(256), 0, stream>>>(w1, w1T, 3072, 4096);
  transpose_f32_bf16<<<dim3(16, 192), dim3(256), 0, stream>>>(w2, w2T, 12288, 1024);
  // qkv = dec @ qkv_w + qkv_b
  gemm_bt<1, false, 1><<<dim3(24, 32), dim3(256), 0, stream>>>(decB, wqkvT, bqkv, qkv, nullptr, 4096, 3072, 1024, zp);
  // attention (pad-keys-only MFMA flash, scrambled output)
  gather_v<<<dim3(16, 8), dim3(256), 0, stream>>>(qkv, pidx, pcnt, Vt);
  attn_mfma<<<dim3(64, 8), dim3(256), 0, stream>>>(qkv, Vt, pidx, pcnt, vecS);
  // attn_out = vecS @ o_w
  gemm_bt<1, false, 1><<<dim3(8, 32), dim3(256), 0, stream>>>(vecS, woT, nullptr, atto, nullptr, 4096, 1024, 1024, zp);
  // x1 = LN1(dec + attn_out) * mask
  ln_kernel<true, false><<<dim3(4096), dim3(256), 0, stream>>>(dec, atto, g1, b1, maskf, x1bf);
  // y = relu(conv1(x1))
  gemm_bt<3, true, 1><<<dim3(32, 32), dim3(256), 0, stream>>>(x1bf, w1T, bc1, ybuf, nullptr, 4096, 4096, 1024, zp);
  // core = conv2(y): split-K=4 (grid 8x32x4 = 1024 blocks), raw partials + reduce
  gemm_bt<3, false, 4><<<dim3(8, 32, 4), dim3(256), 0, stream>>>(ybuf, w2T, nullptr, P0, P1, 4096, 1024, 4096, zp);
  reduce_split4<<<dim3(2048), dim3(256), 0, stream>>>(P0, P1, bc2, core, 4194304, 1024);
  // out = LN2(x1 + core) * mask  -> fp32 d_out
  ln_kernel<false, true><<<dim3(4096), dim3(256), 0, stream>>>(x1bf, core, g2, b2, maskf, (float*)d_out);
}

// Round 5
// 577.093 us; speedup vs baseline: 1.9782x; 1.0147x over previous
//
#include <hip/hip_runtime.h>
#include <cstdint>
#include <cstddef>

typedef float f32x4 __attribute__((ext_vector_type(4)));
typedef __bf16 bf16x8 __attribute__((ext_vector_type(8)));
typedef unsigned short u16;

__device__ __forceinline__ float bf2f(u16 u) {
  union { unsigned int i; float f; } x; x.i = ((unsigned int)u) << 16; return x.f;
}
__device__ __forceinline__ u16 f2bf(float f) {
  union { float f; unsigned int i; } x; x.f = f;
  unsigned int i = x.i;
  i += 0x7fffu + ((i >> 16) & 1u);   // round-to-nearest-even
  return (u16)(i >> 16);
}

#if defined(__has_builtin)
#if __has_builtin(__builtin_amdgcn_global_load_lds)
#define HAS_GLL 1
#endif
#endif

__device__ __forceinline__ void async16(const u16* g, u16* l) {
#ifdef HAS_GLL
  __builtin_amdgcn_global_load_lds((const __attribute__((address_space(1))) void*)(const void*)g,
                                   (__attribute__((address_space(3))) void*)(void*)l, 16, 0, 0);
#else
  *(uint4*)l = *(const uint4*)g;
#endif
}

// CUTLASS-style group-major block swizzle: consecutive dispatch ids cover a
// GM x (ids/GM) m-n patch -> co-resident blocks share A/B panels in L2.
__device__ __forceinline__ void swizzle_mn(int& bm, int& bn) {
  const int num_bn = gridDim.x, num_bm = gridDim.y;
  const int id = blockIdx.x + num_bn * blockIdx.y;
  const int GM = 16;
  const int gid = id / (GM * num_bn);
  const int first = gid * GM;
  int gsz = num_bm - first; if (gsz > GM) gsz = GM;
  bm = first + (id % gsz);
  bn = (id % (GM * num_bn)) / gsz;
}

// ---------------- mask compaction (dtype-width-agnostic) ----------------
__global__ void compact_mask(const unsigned char* __restrict__ mask,
                             int* __restrict__ padIdx, int* __restrict__ padCnt,
                             float* __restrict__ maskf) {
  const int b = blockIdx.x;        // 4 rows
  const int lane = threadIdx.x;    // 64
  int stride = 1;
  if (mask[1] == 0) stride = (mask[4] != 0) ? 4 : 8;
  int cnt = 0;
  for (int s0 = 0; s0 < 1024; s0 += 64) {
    const int s = s0 + lane;
    const bool valid = (mask[(size_t)((b << 10) + s) * stride] != 0);
    maskf[(b << 10) + s] = valid ? 1.f : 0.f;
    const bool pad = !valid;
    const unsigned long long bal = __ballot(pad);
    const int rank = (int)__popcll(bal & ((1ull << lane) - 1ull));
    if (pad) padIdx[(b << 10) + cnt + rank] = s;
    cnt += (int)__popcll(bal);
  }
  if (lane == 0) padCnt[b] = cnt;
}

// ---------------- fp32 -> bf16 convert ----------------
__global__ __launch_bounds__(256)
void f32_to_bf16(const float* __restrict__ in, u16* __restrict__ out, int n4) {
  const int i = blockIdx.x * 256 + threadIdx.x;
  if (i < n4) {
    const float4 v = ((const float4*)in)[i];
    u16 o[4] = { f2bf(v.x), f2bf(v.y), f2bf(v.z), f2bf(v.w) };
    ((ushort4*)out)[i] = *(const ushort4*)o;
  }
}

// ---------------- fp32 transpose+convert: in[R][C] f32 -> out[C][R] bf16 ----------------
__global__ __launch_bounds__(256)
void transpose_f32_bf16(const float* __restrict__ in, u16* __restrict__ out, int R, int C) {
  __shared__ u16 tile[64][65];
  const int r0 = blockIdx.y << 6, c0 = blockIdx.x << 6;
  const int tid = threadIdx.x;
  const int lr = tid >> 3, lc = (tid & 7) << 3;
#pragma unroll
  for (int p = 0; p < 2; ++p) {
    const int row = lr + (p << 5);
    const float4 a = *(const float4*)(in + (size_t)(r0 + row) * C + c0 + lc);
    const float4 bq = *(const float4*)(in + (size_t)(r0 + row) * C + c0 + lc + 4);
    tile[row][lc + 0] = f2bf(a.x); tile[row][lc + 1] = f2bf(a.y);
    tile[row][lc + 2] = f2bf(a.z); tile[row][lc + 3] = f2bf(a.w);
    tile[row][lc + 4] = f2bf(bq.x); tile[row][lc + 5] = f2bf(bq.y);
    tile[row][lc + 6] = f2bf(bq.z); tile[row][lc + 7] = f2bf(bq.w);
  }
  __syncthreads();
#pragma unroll
  for (int p = 0; p < 2; ++p) {
    const int oc = lr + (p << 5);
    u16 tmp[8];
#pragma unroll
    for (int e = 0; e < 8; ++e) tmp[e] = tile[lc + e][oc];
    *(uint4*)(out + (size_t)(c0 + oc) * R + r0 + lc) = *(const uint4*)tmp;
  }
}

// ---------------- GEMM: C[M,N] = A(taps)[M,K] @ B[K,N] (+bias, relu) ----------------
// LDS col-block swizzled; group-major block swizzle for L2 locality.
// SPLITK>1: blockIdx.z selects K-chunk; raw bf16 partial -> P0 (kz=0) / P1+(kz-1)*MN.
template<int NTAPS, bool RELU, int SPLITK, int KORIG>
__global__ __launch_bounds__(256)
void gemm_bt(const u16* __restrict__ A, const u16* __restrict__ BT,
             const float* __restrict__ bias, u16* __restrict__ C, u16* __restrict__ Calt,
             int M, int N, const u16* __restrict__ zp) {
  __shared__ __align__(16) u16 As[128 * 64];
  __shared__ __align__(16) u16 Bs[128 * 64];
  const int tid = threadIdx.x;
  int bm, bn;
  swizzle_mn(bm, bn);
  const int m0 = bm << 7;
  const int n0 = bn << 7;
  const int kz = (SPLITK > 1) ? blockIdx.z : 0;
  const int Ktot = NTAPS * KORIG;
  const int kchunk = Ktot / SPLITK;
  const int lane = tid & 63;
  const int w = tid >> 6;
  const int wm = (w >> 1) << 6;
  const int wn = (w & 1) << 6;
  const int fr = lane & 15;
  const int quad = lane >> 4;
  const int srow = tid >> 3;          // 0..31
  const int scol = (tid & 7) << 3;    // LDS dest col (fixed: lane*16B)
  const int sx = (((tid & 7) ^ (srow & 7)) << 3);   // swizzled source col

  f32x4 acc[4][4] = {};

  const int kbeg = kz * kchunk, kend = kbeg + kchunk;
  for (int k0 = kbeg; k0 < kend; k0 += 64) {
    int t = 0, c0 = k0;
    if (NTAPS == 3) { t = k0 / KORIG; c0 = k0 - t * KORIG; }   // compile-time shifts
#pragma unroll
    for (int i = 0; i < 4; ++i) {
      const int row = srow + (i << 5);
      const u16* src;
      if (NTAPS == 3) {
        const int m = m0 + row;
        const int sp = (m & 1023) + t - 1;
        src = ((unsigned)sp < 1024u) ? (A + (size_t)(m + t - 1) * KORIG + c0 + sx)
                                     : (zp + ((tid & 255) << 3));
      } else {
        src = A + (size_t)(m0 + row) * KORIG + c0 + sx;
      }
      async16(src, &As[(row << 6) + scol]);
    }
#pragma unroll
    for (int i = 0; i < 4; ++i) {
      const int n = srow + (i << 5);
      async16(BT + (size_t)(n0 + n) * Ktot + k0 + sx, &Bs[(n << 6) + scol]);
    }
    asm volatile("s_waitcnt vmcnt(0)" ::: "memory");
    __syncthreads();
#pragma unroll
    for (int ks = 0; ks < 64; ks += 32) {
      const int ccol = ((((ks >> 3) + quad) ^ (fr & 7)) << 3);
      bf16x8 af[4], bfr[4];
#pragma unroll
      for (int mi = 0; mi < 4; ++mi)
        af[mi] = *(const bf16x8*)&As[((wm + (mi << 4) + fr) << 6) + ccol];
#pragma unroll
      for (int ni = 0; ni < 4; ++ni)
        bfr[ni] = *(const bf16x8*)&Bs[((wn + (ni << 4) + fr) << 6) + ccol];
#pragma unroll
      for (int mi = 0; mi < 4; ++mi)
#pragma unroll
        for (int ni = 0; ni < 4; ++ni)
          acc[mi][ni] = __builtin_amdgcn_mfma_f32_16x16x32_bf16(af[mi], bfr[ni], acc[mi][ni], 0, 0, 0);
    }
    __syncthreads();
  }
  const int rbase = m0 + wm + (quad << 2);
  const int cbase = n0 + wn + fr;
  u16* dst = C;
  if (SPLITK > 1 && kz > 0) dst = Calt + (size_t)(kz - 1) * ((size_t)M * N);
#pragma unroll
  for (int ni = 0; ni < 4; ++ni) {
    const int col = cbase + (ni << 4);
    const float bv = (SPLITK == 1 && bias) ? bias[col] : 0.f;
#pragma unroll
    for (int mi = 0; mi < 4; ++mi) {
#pragma unroll
      for (int r = 0; r < 4; ++r) {
        float v = acc[mi][ni][r] + bv;
        if (RELU) v = fmaxf(v, 0.f);
        dst[(size_t)(rbase + (mi << 4) + r) * N + col] = f2bf(v);
      }
    }
  }
}

// ---------------- V^T gather: Vt[(bm*1024+ch)][512] = V[b, padIdx[mb][j], ch] ----------------
__global__ __launch_bounds__(256)
void gather_v(const u16* __restrict__ qkv, const int* __restrict__ padIdx,
              const int* __restrict__ padCnt, u16* __restrict__ Vt) {
  const int bm = blockIdx.x;          // 16: b*4+mb
  const int jt = blockIdx.y;          // 8
  const int b = bm >> 2, mb = bm & 3;
  const int npad = padCnt[mb];
  const int npadR = (npad + 63) & ~63;
  if (jt * 64 >= npadR) return;
  const int tid = threadIdx.x;
  __shared__ int rows[64];
  if (tid < 64) {
    const int j = jt * 64 + tid;
    const int jj = j < npad ? j : npad - 1;
    rows[tid] = padIdx[(mb << 10) + jj];
  }
  __shared__ u16 tile[64][72];
  for (int c = 0; c < 16; ++c) {
    const int ch0 = c << 6;
    __syncthreads();
#pragma unroll
    for (int p = 0; p < 2; ++p) {
      const int r = (tid >> 3) + (p << 5);
      const int ch = (tid & 7) << 3;
      const uint4 v = *(const uint4*)(qkv + (size_t)((b << 10) + rows[r]) * 3072 + 2048 + ch0 + ch);
      const u16* us = (const u16*)&v;
#pragma unroll
      for (int e = 0; e < 8; ++e) tile[r][ch + e] = us[e];
    }
    __syncthreads();
#pragma unroll
    for (int p = 0; p < 2; ++p) {
      const int r = (tid >> 3) + (p << 5);   // channel row within chunk
      const int jc = (tid & 7) << 3;
      u16 tmp[8];
#pragma unroll
      for (int e = 0; e < 8; ++e) tmp[e] = tile[jc + e][r];
      *(uint4*)(Vt + (size_t)((bm << 10) + ch0 + r) * 512 + jt * 64 + jc) = *(const uint4*)tmp;
    }
  }
}

// ---------------- MFMA flash attention over PAD keys (faithful to mask bug) ----------------
// flat head i = b*16+h; mask batch = out batch = h&3; out head slot = i>>2
__global__ __launch_bounds__(256)
void attn_mfma(const u16* __restrict__ qkv, const u16* __restrict__ Vt,
               const int* __restrict__ padIdx, const int* __restrict__ padCnt,
               u16* __restrict__ vecS) {
  __shared__ __align__(16) u16 Ks[64 * 64];
  __shared__ __align__(16) u16 Vts[64 * 64];
  __shared__ __align__(16) u16 Ps[4][32 * 88];   // stride 88: 16B-aligned rows
  __shared__ int rowsIdx[512];
  const int i = blockIdx.x;     // 64
  const int qt = blockIdx.y;    // 8
  const int b = i >> 4, h = i & 15;
  const int mb = h & 3, bm = (b << 2) + mb;
  const int h_out = i >> 2;
  const int npad = padCnt[mb];
  const int nkt = (npad + 63) >> 6;
  const int tid = threadIdx.x;
  const int w = tid >> 6, lane = tid & 63;
  const int fr = lane & 15, quad = lane >> 4, fko = quad << 3;
  const int srow = tid >> 3, scol = (tid & 7) << 3;
  const int sx = (((tid & 7) ^ (srow & 7)) << 3);   // swizzled source col

  // stage clamped pad indices
#pragma unroll
  for (int p = 0; p < 2; ++p) {
    const int j = (p << 8) + tid;
    const int jj = j < npad ? j : npad - 1;
    rowsIdx[j] = padIdx[(mb << 10) + jj];
  }

  // Q A-fragments (registers for the whole block)
  const int qw = (qt << 7) + (w << 5);
  bf16x8 qf[2][2];
#pragma unroll
  for (int rt = 0; rt < 2; ++rt)
#pragma unroll
    for (int ks = 0; ks < 2; ++ks)
      qf[rt][ks] = *(const bf16x8*)(qkv + (size_t)((b << 10) + qw + (rt << 4) + fr) * 3072 +
                                    (h << 6) + (ks << 5) + fko);

  f32x4 O[2][4];
  float mrun[2][4], lrun[2][4];
#pragma unroll
  for (int rt = 0; rt < 2; ++rt)
#pragma unroll
    for (int r = 0; r < 4; ++r) {
      mrun[rt][r] = -1e30f; lrun[rt][r] = 0.f;
#pragma unroll
      for (int dt = 0; dt < 4; ++dt) O[rt][dt][r] = 0.f;
    }
  __syncthreads();   // rowsIdx visible

  for (int kt = 0; kt < nkt; ++kt) {
    // stage K (direct swizzled gather) and V^T tiles
#pragma unroll
    for (int p = 0; p < 2; ++p) {
      const int r = srow + (p << 5);
      const int grow = rowsIdx[(kt << 6) + r];
      async16(qkv + (size_t)((b << 10) + grow) * 3072 + 1024 + (h << 6) + sx,
              &Ks[(r << 6) + scol]);
      async16(Vt + (size_t)((bm << 10) + (h << 6) + r) * 512 + (kt << 6) + sx,
              &Vts[(r << 6) + scol]);
    }
    asm volatile("s_waitcnt vmcnt(0)" ::: "memory");
    __syncthreads();

    // S = Q @ K^T
    f32x4 S[2][4];
#pragma unroll
    for (int rt = 0; rt < 2; ++rt)
#pragma unroll
      for (int nt = 0; nt < 4; ++nt)
#pragma unroll
        for (int r = 0; r < 4; ++r) S[rt][nt][r] = 0.f;
#pragma unroll
    for (int ks = 0; ks < 2; ++ks) {
      const int ccol = ((((ks << 2) + quad) ^ (fr & 7)) << 3);
      bf16x8 bfr[4];
#pragma unroll
      for (int nt = 0; nt < 4; ++nt)
        bfr[nt] = *(const bf16x8*)&Ks[(((nt << 4) + fr) << 6) + ccol];
#pragma unroll
      for (int rt = 0; rt < 2; ++rt)
#pragma unroll
        for (int nt = 0; nt < 4; ++nt)
          S[rt][nt] = __builtin_amdgcn_mfma_f32_16x16x32_bf16(qf[rt][ks], bfr[nt], S[rt][nt], 0, 0, 0);
    }

    // scale + tail mask
#pragma unroll
    for (int nt = 0; nt < 4; ++nt) {
      const int key = (kt << 6) + (nt << 4) + fr;
      const bool dead = (key >= npad);
#pragma unroll
      for (int rt = 0; rt < 2; ++rt)
#pragma unroll
        for (int r = 0; r < 4; ++r) {
          float s = S[rt][nt][r] * 0.125f;
          S[rt][nt][r] = dead ? -1e30f : s;
        }
    }

    // online softmax per q-row (rows live in quad; cols in lane&15)
#pragma unroll
    for (int rt = 0; rt < 2; ++rt) {
#pragma unroll
      for (int r = 0; r < 4; ++r) {
        float mx = fmaxf(fmaxf(S[rt][0][r], S[rt][1][r]), fmaxf(S[rt][2][r], S[rt][3][r]));
#pragma unroll
        for (int off = 1; off <= 8; off <<= 1) mx = fmaxf(mx, __shfl_xor(mx, off, 64));
        const float mnew = fmaxf(mrun[rt][r], mx);
        const float alpha = __expf(mrun[rt][r] - mnew);
        mrun[rt][r] = mnew;
        float rsum = 0.f;
#pragma unroll
        for (int nt = 0; nt < 4; ++nt) {
          const float p_ = __expf(S[rt][nt][r] - mnew);
          S[rt][nt][r] = p_;
          rsum += p_;
        }
#pragma unroll
        for (int off = 1; off <= 8; off <<= 1) rsum += __shfl_xor(rsum, off, 64);
        lrun[rt][r] = lrun[rt][r] * alpha + rsum;
#pragma unroll
        for (int dt = 0; dt < 4; ++dt) O[rt][dt][r] *= alpha;
      }
    }

    // P -> wave-private LDS (C-layout -> A-layout transpose)
    u16* ps = &Ps[w][0];
#pragma unroll
    for (int rt = 0; rt < 2; ++rt)
#pragma unroll
      for (int nt = 0; nt < 4; ++nt)
#pragma unroll
        for (int r = 0; r < 4; ++r)
          ps[((rt << 4) + (quad << 2) + r) * 88 + (nt << 4) + fr] = f2bf(S[rt][nt][r]);
    asm volatile("s_waitcnt lgkmcnt(0)" ::: "memory");

    // O += P @ V
#pragma unroll
    for (int ks = 0; ks < 2; ++ks) {
      const int ccol = ((((ks << 2) + quad) ^ (fr & 7)) << 3);
      bf16x8 af[2], bv[4];
#pragma unroll
      for (int rt = 0; rt < 2; ++rt)
        af[rt] = *(const bf16x8*)&ps[((rt << 4) + fr) * 88 + (ks << 5) + fko];
#pragma unroll
      for (int dt = 0; dt < 4; ++dt)
        bv[dt] = *(const bf16x8*)&Vts[(((dt << 4) + fr) << 6) + ccol];
#pragma unroll
      for (int rt = 0; rt < 2; ++rt)
#pragma unroll
        for (int dt = 0; dt < 4; ++dt)
          O[rt][dt] = __builtin_amdgcn_mfma_f32_16x16x32_bf16(af[rt], bv[dt], O[rt][dt], 0, 0, 0);
    }
    __syncthreads();   // protect Ks/Vts before next staging
  }

  // epilogue: normalize + scrambled write
#pragma unroll
  for (int rt = 0; rt < 2; ++rt)
#pragma unroll
    for (int r = 0; r < 4; ++r) {
      const float inv = 1.f / lrun[rt][r];
      const int q = qw + (rt << 4) + (quad << 2) + r;
      u16* orow = vecS + (size_t)((mb << 10) + q) * 1024 + (h_out << 6);
#pragma unroll
      for (int dt = 0; dt < 4; ++dt)
        orow[(dt << 4) + fr] = f2bf(O[rt][dt][r] * inv);
    }
}

// ---------------- residual + layernorm + mask-mul ----------------
template<bool XF32, bool OUTF32>
__global__ __launch_bounds__(256)
void ln_kernel(const void* __restrict__ Xv, const u16* __restrict__ Yd,
               const float* __restrict__ g, const float* __restrict__ be,
               const float* __restrict__ maskf, void* __restrict__ outv) {
  const int r = blockIdx.x;
  const int tid = threadIdx.x;
  const size_t base = (size_t)r << 10;
  const float* Xf = (const float*)Xv;
  const u16* Xb = (const u16*)Xv;
  float x[4];
  float s1 = 0.f, s2 = 0.f;
#pragma unroll
  for (int j = 0; j < 4; ++j) {
    const int c = (tid << 2) + j;
    const float xv = XF32 ? Xf[base + c] : bf2f(Xb[base + c]);
    const float v = xv + bf2f(Yd[base + c]);
    x[j] = v; s1 += v; s2 += v * v;
  }
#pragma unroll
  for (int off = 32; off > 0; off >>= 1) { s1 += __shfl_xor(s1, off, 64); s2 += __shfl_xor(s2, off, 64); }
  __shared__ float rs1[4], rs2[4];
  if ((tid & 63) == 0) { rs1[tid >> 6] = s1; rs2[tid >> 6] = s2; }
  __syncthreads();
  s1 = rs1[0] + rs1[1] + rs1[2] + rs1[3];
  s2 = rs2[0] + rs2[1] + rs2[2] + rs2[3];
  const float mean = s1 * (1.f / 1024.f);
  const float var = s2 * (1.f / 1024.f) - mean * mean;
  const float rstd = rsqrtf(var + 1e-3f);
  const float mv = maskf[r];
#pragma unroll
  for (int j = 0; j < 4; ++j) {
    const int c = (tid << 2) + j;
    const float y = ((x[j] - mean) * rstd * g[c] + be[c]) * mv;
    if (OUTF32) ((float*)outv)[base + c] = y;
    else ((u16*)outv)[base + c] = f2bf(y);
  }
}

// ---------------- LN2 fused with split-K reduce: LN(X + sum(P)+bias) * mask -> f32 ----------------
__global__ __launch_bounds__(256)
void ln_reduce4_kernel(const u16* __restrict__ X, const u16* __restrict__ P0,
                       const u16* __restrict__ P1, int MN,
                       const float* __restrict__ bias,
                       const float* __restrict__ g, const float* __restrict__ be,
                       const float* __restrict__ maskf, float* __restrict__ outv) {
  const int r = blockIdx.x;
  const int tid = threadIdx.x;
  const size_t base = (size_t)r << 10;
  float x[4];
  float s1 = 0.f, s2 = 0.f;
#pragma unroll
  for (int j = 0; j < 4; ++j) {
    const int c = (tid << 2) + j;
    const size_t idx = base + c;
    const float core = bf2f(P0[idx]) + bf2f(P1[idx]) + bf2f(P1[MN + idx]) +
                       bf2f(P1[2 * (size_t)MN + idx]) + bias[c];
    const float v = bf2f(X[idx]) + core;
    x[j] = v; s1 += v; s2 += v * v;
  }
#pragma unroll
  for (int off = 32; off > 0; off >>= 1) { s1 += __shfl_xor(s1, off, 64); s2 += __shfl_xor(s2, off, 64); }
  __shared__ float rs1[4], rs2[4];
  if ((tid & 63) == 0) { rs1[tid >> 6] = s1; rs2[tid >> 6] = s2; }
  __syncthreads();
  s1 = rs1[0] + rs1[1] + rs1[2] + rs1[3];
  s2 = rs2[0] + rs2[1] + rs2[2] + rs2[3];
  const float mean = s1 * (1.f / 1024.f);
  const float var = s2 * (1.f / 1024.f) - mean * mean;
  const float rstd = rsqrtf(var + 1e-3f);
  const float mv = maskf[r];
#pragma unroll
  for (int j = 0; j < 4; ++j) {
    const int c = (tid << 2) + j;
    outv[base + c] = ((x[j] - mean) * rstd * g[c] + be[c]) * mv;
  }
}

extern "C" void kernel_launch(void* const* d_in, const int* in_sizes, int n_in,
                              void* d_out, int out_size, void* d_ws, size_t ws_size,
                              hipStream_t stream) {
  (void)in_sizes; (void)n_in; (void)out_size; (void)ws_size;
  const float* dec  = (const float*)d_in[0];
  const unsigned char* mask = (const unsigned char*)d_in[1];
  const float* wqkv = (const float*)d_in[2];
  const float* bqkv = (const float*)d_in[3];
  const float* wo   = (const float*)d_in[4];
  const float* g1   = (const float*)d_in[5];
  const float* b1   = (const float*)d_in[6];
  const float* w1   = (const float*)d_in[7];
  const float* bc1  = (const float*)d_in[8];
  const float* w2   = (const float*)d_in[9];
  const float* bc2  = (const float*)d_in[10];
  const float* g2   = (const float*)d_in[11];
  const float* b2   = (const float*)d_in[12];
  char* ws = (char*)d_ws;
  // workspace layout (bytes), peak 117,506,048
  u16*   zp    = (u16*)(ws + 0);            // 4 KB zero page
  int*   pcnt  = (int*)(ws + 4096);
  float* maskf = (float*)(ws + 8192);       // [4096]
  int*   pidx  = (int*)(ws + 24576);        // [4][1024]
  u16*   decB  = (u16*)(ws + 65536);        // [4096][1024]   ends 8454144   (dead after QKV gemm)
  u16*   wqkvT = (u16*)(ws + 8454144);      // [3072][1024]   ends 14745600  (dead after QKV gemm)
  u16*   woT   = (u16*)(ws + 14745600);     // [1024][1024]   ends 16842752  (dead after atto gemm)
  u16*   w1T   = (u16*)(ws + 16842752);     // [4096][3072]   ends 42008576  (dead after conv1)
  u16*   w2T   = (u16*)(ws + 42008576);     // [1024][12288]  ends 67174400
  u16*   qkv   = (u16*)(ws + 67174400);     // [4096][3072]   ends 92340224  (dead after attn)
  u16*   Vt    = (u16*)(ws + 92340224);     // [16*1024][512] ends 109117440 (dead after attn)
  u16*   vecS  = (u16*)(ws + 109117440);    // [4096][1024]   ends 117506048 (dead after atto gemm)
  u16*   atto  = (u16*)(ws + 65536);        // reuses decB region (dead after LN1)
  u16*   x1bf  = (u16*)(ws + 8454144);      // reuses wqkvT+woT region
  u16*   ybuf  = (u16*)(ws + 67174400);     // [4096][4096] reuses qkv+Vt
  u16*   P0    = (u16*)(ws + 65536);        // split-K partial kz=0 (decB/atto region)
  u16*   P1    = (u16*)(ws + 16842752);     // split-K partials kz=1..3 (w1T region)

  hipMemsetAsync(zp, 0, 4096, stream);
  compact_mask<<<dim3(4), dim3(64), 0, stream>>>(mask, pidx, pcnt, maskf);
  f32_to_bf16<<<dim3(4096), dim3(256), 0, stream>>>(dec, decB, 1048576);
  transpose_f32_bf16<<<dim3(48, 16), dim3(256), 0, stream>>>(wqkv, wqkvT, 1024, 3072);
  transpose_f32_bf16<<<dim3(16, 16), dim3(256), 0, stream>>>(wo, woT, 1024, 1024);
  transpose_f32_bf16<<<dim3(64, 48), dim3(256), 0, stream>>>(w1, w1T, 3072, 4096);
  transpose_f32_bf16<<<dim3(16, 192), dim3(256), 0, stream>>>(w2, w2T, 12288, 1024);
  // qkv = dec @ qkv_w + qkv_b
  gemm_bt<1, false, 1, 1024><<<dim3(24, 32), dim3(256), 0, stream>>>(decB, wqkvT, bqkv, qkv, nullptr, 4096, 3072, zp);
  // attention (pad-keys-only MFMA flash, scrambled output)
  gather_v<<<dim3(16, 8), dim3(256), 0, stream>>>(qkv, pidx, pcnt, Vt);
  attn_mfma<<<dim3(64, 8), dim3(256), 0, stream>>>(qkv, Vt, pidx, pcnt, vecS);
  // attn_out = vecS @ o_w
  gemm_bt<1, false, 1, 1024><<<dim3(8, 32), dim3(256), 0, stream>>>(vecS, woT, nullptr, atto, nullptr, 4096, 1024, zp);
  // x1 = LN1(dec + attn_out) * mask
  ln_kernel<true, false><<<dim3(4096), dim3(256), 0, stream>>>(dec, atto, g1, b1, maskf, x1bf);
  // y = relu(conv1(x1))
  gemm_bt<3, true, 1, 1024><<<dim3(32, 32), dim3(256), 0, stream>>>(x1bf, w1T, bc1, ybuf, nullptr, 4096, 4096, zp);
  // core partials = conv2(y): split-K=4 (grid 8x32x4 = 1024 blocks)
  gemm_bt<3, false, 4, 4096><<<dim3(8, 32, 4), dim3(256), 0, stream>>>(ybuf, w2T, nullptr, P0, P1, 4096, 1024, zp);
  // out = LN2(x1 + sum(partials)+bias) * mask  -> fp32 d_out (fused reduce)
  ln_reduce4_kernel<<<dim3(4096), dim3(256), 0, stream>>>(x1bf, P0, P1, 4194304, bc2, g2, b2, maskf, (float*)d_out);
}

// Round 6
// 540.342 us; speedup vs baseline: 2.1128x; 1.0680x over previous
//
#include <hip/hip_runtime.h>
#include <cstdint>
#include <cstddef>

typedef float f32x4 __attribute__((ext_vector_type(4)));
typedef __bf16 bf16x8 __attribute__((ext_vector_type(8)));
typedef unsigned short u16;

__device__ __forceinline__ float bf2f(u16 u) {
  union { unsigned int i; float f; } x; x.i = ((unsigned int)u) << 16; return x.f;
}
__device__ __forceinline__ u16 f2bf(float f) {
  union { float f; unsigned int i; } x; x.f = f;
  unsigned int i = x.i;
  i += 0x7fffu + ((i >> 16) & 1u);   // round-to-nearest-even
  return (u16)(i >> 16);
}

#if defined(__has_builtin)
#if __has_builtin(__builtin_amdgcn_global_load_lds)
#define HAS_GLL 1
#endif
#endif

__device__ __forceinline__ void async16(const u16* g, u16* l) {
#ifdef HAS_GLL
  __builtin_amdgcn_global_load_lds((const __attribute__((address_space(1))) void*)(const void*)g,
                                   (__attribute__((address_space(3))) void*)(void*)l, 16, 0, 0);
#else
  *(uint4*)l = *(const uint4*)g;
#endif
}

// ---------------- mask compaction (dtype-width-agnostic) ----------------
__global__ void compact_mask(const unsigned char* __restrict__ mask,
                             int* __restrict__ padIdx, int* __restrict__ padCnt,
                             float* __restrict__ maskf) {
  const int b = blockIdx.x;        // 4 rows
  const int lane = threadIdx.x;    // 64
  int stride = 1;
  if (mask[1] == 0) stride = (mask[4] != 0) ? 4 : 8;
  int cnt = 0;
  for (int s0 = 0; s0 < 1024; s0 += 64) {
    const int s = s0 + lane;
    const bool valid = (mask[(size_t)((b << 10) + s) * stride] != 0);
    maskf[(b << 10) + s] = valid ? 1.f : 0.f;
    const bool pad = !valid;
    const unsigned long long bal = __ballot(pad);
    const int rank = (int)__popcll(bal & ((1ull << lane) - 1ull));
    if (pad) padIdx[(b << 10) + cnt + rank] = s;
    cnt += (int)__popcll(bal);
  }
  if (lane == 0) padCnt[b] = cnt;
}

// ---------------- fp32 -> bf16 convert ----------------
__global__ __launch_bounds__(256)
void f32_to_bf16(const float* __restrict__ in, u16* __restrict__ out, int n4) {
  const int i = blockIdx.x * 256 + threadIdx.x;
  if (i < n4) {
    const float4 v = ((const float4*)in)[i];
    u16 o[4] = { f2bf(v.x), f2bf(v.y), f2bf(v.z), f2bf(v.w) };
    ((ushort4*)out)[i] = *(const ushort4*)o;
  }
}

// ---------------- fp32 transpose+convert: in[R][C] f32 -> out[C][R] bf16 ----------------
__global__ __launch_bounds__(256)
void transpose_f32_bf16(const float* __restrict__ in, u16* __restrict__ out, int R, int C) {
  __shared__ u16 tile[64][65];
  const int r0 = blockIdx.y << 6, c0 = blockIdx.x << 6;
  const int tid = threadIdx.x;
  const int lr = tid >> 3, lc = (tid & 7) << 3;
#pragma unroll
  for (int p = 0; p < 2; ++p) {
    const int row = lr + (p << 5);
    const float4 a = *(const float4*)(in + (size_t)(r0 + row) * C + c0 + lc);
    const float4 bq = *(const float4*)(in + (size_t)(r0 + row) * C + c0 + lc + 4);
    tile[row][lc + 0] = f2bf(a.x); tile[row][lc + 1] = f2bf(a.y);
    tile[row][lc + 2] = f2bf(a.z); tile[row][lc + 3] = f2bf(a.w);
    tile[row][lc + 4] = f2bf(bq.x); tile[row][lc + 5] = f2bf(bq.y);
    tile[row][lc + 6] = f2bf(bq.z); tile[row][lc + 7] = f2bf(bq.w);
  }
  __syncthreads();
#pragma unroll
  for (int p = 0; p < 2; ++p) {
    const int oc = lr + (p << 5);
    u16 tmp[8];
#pragma unroll
    for (int e = 0; e < 8; ++e) tmp[e] = tile[lc + e][oc];
    *(uint4*)(out + (size_t)(c0 + oc) * R + r0 + lc) = *(const uint4*)tmp;
  }
}

// ---------------- GEMM: C[M,N] = A(taps)[M,K] @ B[K,N] (+bias, relu) ----------------
// Tap-phase K-loop: per segment, fixed tap shift; per-row pointers hoisted and
// incremented (+64 elts/iter). LDS col-block swizzled. Compile-time block swizzle.
// SPLITK>1: blockIdx.z selects K-chunk; raw bf16 partial -> C (kz=0) / Calt+(kz-1)*MN.
template<int NTAPS, bool RELU, int SPLITK, int KORIG, int NBN>
__global__ __launch_bounds__(256)
void gemm_bt(const u16* __restrict__ A, const u16* __restrict__ BT,
             const float* __restrict__ bias, u16* __restrict__ C, u16* __restrict__ Calt,
             int M, int N, const u16* __restrict__ zp) {
  __shared__ __align__(16) u16 As[128 * 64];
  __shared__ __align__(16) u16 Bs[128 * 64];
  const int tid = threadIdx.x;
  // group-major block swizzle (GM=16 m-tiles per group), compile-time NBN
  const int id = blockIdx.x + NBN * blockIdx.y;
  const int bm = ((id / (16 * NBN)) << 4) + (id & 15);
  const int bn = (id % (16 * NBN)) >> 4;
  const int m0 = bm << 7;
  const int n0 = bn << 7;
  const int kz = (SPLITK > 1) ? blockIdx.z : 0;
  constexpr int Ktot = NTAPS * KORIG;
  constexpr int kchunk = Ktot / SPLITK;
  const int lane = tid & 63;
  const int w = tid >> 6;
  const int wm = (w >> 1) << 6;
  const int wn = (w & 1) << 6;
  const int fr = lane & 15;
  const int quad = lane >> 4;
  const int srow = tid >> 3;          // 0..31
  const int scol = (tid & 7) << 3;    // LDS dest col (fixed: lane*16B)
  const int sx = (((tid & 7) ^ (srow & 7)) << 3);   // swizzled source col

  f32x4 acc[4][4] = {};

  const int kbeg = kz * kchunk, kend = kbeg + kchunk;
  int k = kbeg;
  while (k < kend) {
    const int t = (NTAPS == 3) ? (k / KORIG) : 0;
    const int seg_end = (NTAPS == 3) ? min(kend, (t + 1) * KORIG) : kend;
    const int c0 = k - t * KORIG;
    // hoist per-row pointers for this tap phase
    const u16* aptr[4];
    const u16* bptr[4];
#pragma unroll
    for (int i = 0; i < 4; ++i) {
      const int row = srow + (i << 5);
      if (NTAPS == 3) {
        const int m = m0 + row;
        const int sp = (m & 1023) + t - 1;
        aptr[i] = ((unsigned)sp < 1024u) ? (A + (size_t)(m + t - 1) * KORIG + c0 + sx)
                                         : (zp + ((tid & 255) << 3));
      } else {
        aptr[i] = A + (size_t)(m0 + row) * KORIG + k + sx;
      }
      bptr[i] = BT + (size_t)(n0 + row) * Ktot + k + sx;
    }
    for (; k < seg_end; k += 64) {
#pragma unroll
      for (int i = 0; i < 4; ++i) {
        const int row = srow + (i << 5);
        async16(aptr[i], &As[(row << 6) + scol]);
        async16(bptr[i], &Bs[(row << 6) + scol]);
        aptr[i] += 64; bptr[i] += 64;
      }
      asm volatile("s_waitcnt vmcnt(0)" ::: "memory");
      __syncthreads();
#pragma unroll
      for (int ks = 0; ks < 64; ks += 32) {
        const int ccol = ((((ks >> 3) + quad) ^ (fr & 7)) << 3);
        bf16x8 af[4], bfr[4];
#pragma unroll
        for (int mi = 0; mi < 4; ++mi)
          af[mi] = *(const bf16x8*)&As[((wm + (mi << 4) + fr) << 6) + ccol];
#pragma unroll
        for (int ni = 0; ni < 4; ++ni)
          bfr[ni] = *(const bf16x8*)&Bs[((wn + (ni << 4) + fr) << 6) + ccol];
#pragma unroll
        for (int mi = 0; mi < 4; ++mi)
#pragma unroll
          for (int ni = 0; ni < 4; ++ni)
            acc[mi][ni] = __builtin_amdgcn_mfma_f32_16x16x32_bf16(af[mi], bfr[ni], acc[mi][ni], 0, 0, 0);
      }
      __syncthreads();
    }
  }
  const int rbase = m0 + wm + (quad << 2);
  const int cbase = n0 + wn + fr;
  u16* dst = C;
  if (SPLITK > 1 && kz > 0) dst = Calt + (size_t)(kz - 1) * ((size_t)M * N);
#pragma unroll
  for (int ni = 0; ni < 4; ++ni) {
    const int col = cbase + (ni << 4);
    const float bv = (SPLITK == 1 && bias) ? bias[col] : 0.f;
#pragma unroll
    for (int mi = 0; mi < 4; ++mi) {
#pragma unroll
      for (int r = 0; r < 4; ++r) {
        float v = acc[mi][ni][r] + bv;
        if (RELU) v = fmaxf(v, 0.f);
        dst[(size_t)(rbase + (mi << 4) + r) * N + col] = f2bf(v);
      }
    }
  }
}

// ---------------- V^T gather: Vt[(bm*1024+ch)][512] = V[b, padIdx[mb][j], ch] ----------------
__global__ __launch_bounds__(256)
void gather_v(const u16* __restrict__ qkv, const int* __restrict__ padIdx,
              const int* __restrict__ padCnt, u16* __restrict__ Vt) {
  const int bm = blockIdx.x;          // 16: b*4+mb
  const int jt = blockIdx.y;          // 8
  const int b = bm >> 2, mb = bm & 3;
  const int npad = padCnt[mb];
  const int npadR = (npad + 63) & ~63;
  if (jt * 64 >= npadR) return;
  const int tid = threadIdx.x;
  __shared__ int rows[64];
  if (tid < 64) {
    const int j = jt * 64 + tid;
    const int jj = j < npad ? j : npad - 1;
    rows[tid] = padIdx[(mb << 10) + jj];
  }
  __shared__ u16 tile[64][72];
  for (int c = 0; c < 16; ++c) {
    const int ch0 = c << 6;
    __syncthreads();
#pragma unroll
    for (int p = 0; p < 2; ++p) {
      const int r = (tid >> 3) + (p << 5);
      const int ch = (tid & 7) << 3;
      const uint4 v = *(const uint4*)(qkv + (size_t)((b << 10) + rows[r]) * 3072 + 2048 + ch0 + ch);
      const u16* us = (const u16*)&v;
#pragma unroll
      for (int e = 0; e < 8; ++e) tile[r][ch + e] = us[e];
    }
    __syncthreads();
#pragma unroll
    for (int p = 0; p < 2; ++p) {
      const int r = (tid >> 3) + (p << 5);   // channel row within chunk
      const int jc = (tid & 7) << 3;
      u16 tmp[8];
#pragma unroll
      for (int e = 0; e < 8; ++e) tmp[e] = tile[jc + e][r];
      *(uint4*)(Vt + (size_t)((bm << 10) + ch0 + r) * 512 + jt * 64 + jc) = *(const uint4*)tmp;
    }
  }
}

// ---------------- MFMA flash attention over PAD keys (faithful to mask bug) ----------------
// flat head i = b*16+h; mask batch = out batch = h&3; out head slot = i>>2
__global__ __launch_bounds__(256)
void attn_mfma(const u16* __restrict__ qkv, const u16* __restrict__ Vt,
               const int* __restrict__ padIdx, const int* __restrict__ padCnt,
               u16* __restrict__ vecS) {
  __shared__ __align__(16) u16 Ks[64 * 64];
  __shared__ __align__(16) u16 Vts[64 * 64];
  __shared__ __align__(16) u16 Ps[4][32 * 88];   // stride 88: 16B-aligned rows
  __shared__ int rowsIdx[512];
  const int i = blockIdx.x;     // 64
  const int qt = blockIdx.y;    // 8
  const int b = i >> 4, h = i & 15;
  const int mb = h & 3, bm = (b << 2) + mb;
  const int h_out = i >> 2;
  const int npad = padCnt[mb];
  const int nkt = (npad + 63) >> 6;
  const int tid = threadIdx.x;
  const int w = tid >> 6, lane = tid & 63;
  const int fr = lane & 15, quad = lane >> 4, fko = quad << 3;
  const int srow = tid >> 3, scol = (tid & 7) << 3;
  const int sx = (((tid & 7) ^ (srow & 7)) << 3);   // swizzled source col

  // stage clamped pad indices
#pragma unroll
  for (int p = 0; p < 2; ++p) {
    const int j = (p << 8) + tid;
    const int jj = j < npad ? j : npad - 1;
    rowsIdx[j] = padIdx[(mb << 10) + jj];
  }

  // Q A-fragments (registers for the whole block)
  const int qw = (qt << 7) + (w << 5);
  bf16x8 qf[2][2];
#pragma unroll
  for (int rt = 0; rt < 2; ++rt)
#pragma unroll
    for (int ks = 0; ks < 2; ++ks)
      qf[rt][ks] = *(const bf16x8*)(qkv + (size_t)((b << 10) + qw + (rt << 4) + fr) * 3072 +
                                    (h << 6) + (ks << 5) + fko);

  f32x4 O[2][4];
  float mrun[2][4], lrun[2][4];
#pragma unroll
  for (int rt = 0; rt < 2; ++rt)
#pragma unroll
    for (int r = 0; r < 4; ++r) {
      mrun[rt][r] = -1e30f; lrun[rt][r] = 0.f;
#pragma unroll
      for (int dt = 0; dt < 4; ++dt) O[rt][dt][r] = 0.f;
    }
  __syncthreads();   // rowsIdx visible

  for (int kt = 0; kt < nkt; ++kt) {
    // stage K (direct swizzled gather) and V^T tiles
#pragma unroll
    for (int p = 0; p < 2; ++p) {
      const int r = srow + (p << 5);
      const int grow = rowsIdx[(kt << 6) + r];
      async16(qkv + (size_t)((b << 10) + grow) * 3072 + 1024 + (h << 6) + sx,
              &Ks[(r << 6) + scol]);
      async16(Vt + (size_t)((bm << 10) + (h << 6) + r) * 512 + (kt << 6) + sx,
              &Vts[(r << 6) + scol]);
    }
    asm volatile("s_waitcnt vmcnt(0)" ::: "memory");
    __syncthreads();

    // S = Q @ K^T
    f32x4 S[2][4];
#pragma unroll
    for (int rt = 0; rt < 2; ++rt)
#pragma unroll
      for (int nt = 0; nt < 4; ++nt)
#pragma unroll
        for (int r = 0; r < 4; ++r) S[rt][nt][r] = 0.f;
#pragma unroll
    for (int ks = 0; ks < 2; ++ks) {
      const int ccol = ((((ks << 2) + quad) ^ (fr & 7)) << 3);
      bf16x8 bfr[4];
#pragma unroll
      for (int nt = 0; nt < 4; ++nt)
        bfr[nt] = *(const bf16x8*)&Ks[(((nt << 4) + fr) << 6) + ccol];
#pragma unroll
      for (int rt = 0; rt < 2; ++rt)
#pragma unroll
        for (int nt = 0; nt < 4; ++nt)
          S[rt][nt] = __builtin_amdgcn_mfma_f32_16x16x32_bf16(qf[rt][ks], bfr[nt], S[rt][nt], 0, 0, 0);
    }

    // scale + tail mask
#pragma unroll
    for (int nt = 0; nt < 4; ++nt) {
      const int key = (kt << 6) + (nt << 4) + fr;
      const bool dead = (key >= npad);
#pragma unroll
      for (int rt = 0; rt < 2; ++rt)
#pragma unroll
        for (int r = 0; r < 4; ++r) {
          float s = S[rt][nt][r] * 0.125f;
          S[rt][nt][r] = dead ? -1e30f : s;
        }
    }

    // online softmax per q-row (rows live in quad; cols in lane&15)
#pragma unroll
    for (int rt = 0; rt < 2; ++rt) {
#pragma unroll
      for (int r = 0; r < 4; ++r) {
        float mx = fmaxf(fmaxf(S[rt][0][r], S[rt][1][r]), fmaxf(S[rt][2][r], S[rt][3][r]));
#pragma unroll
        for (int off = 1; off <= 8; off <<= 1) mx = fmaxf(mx, __shfl_xor(mx, off, 64));
        const float mnew = fmaxf(mrun[rt][r], mx);
        const float alpha = __expf(mrun[rt][r] - mnew);
        mrun[rt][r] = mnew;
        float rsum = 0.f;
#pragma unroll
        for (int nt = 0; nt < 4; ++nt) {
          const float p_ = __expf(S[rt][nt][r] - mnew);
          S[rt][nt][r] = p_;
          rsum += p_;
        }
#pragma unroll
        for (int off = 1; off <= 8; off <<= 1) rsum += __shfl_xor(rsum, off, 64);
        lrun[rt][r] = lrun[rt][r] * alpha + rsum;
#pragma unroll
        for (int dt = 0; dt < 4; ++dt) O[rt][dt][r] *= alpha;
      }
    }

    // P -> wave-private LDS (C-layout -> A-layout transpose)
    u16* ps = &Ps[w][0];
#pragma unroll
    for (int rt = 0; rt < 2; ++rt)
#pragma unroll
      for (int nt = 0; nt < 4; ++nt)
#pragma unroll
        for (int r = 0; r < 4; ++r)
          ps[((rt << 4) + (quad << 2) + r) * 88 + (nt << 4) + fr] = f2bf(S[rt][nt][r]);
    asm volatile("s_waitcnt lgkmcnt(0)" ::: "memory");

    // O += P @ V
#pragma unroll
    for (int ks = 0; ks < 2; ++ks) {
      const int ccol = ((((ks << 2) + quad) ^ (fr & 7)) << 3);
      bf16x8 af[2], bv[4];
#pragma unroll
      for (int rt = 0; rt < 2; ++rt)
        af[rt] = *(const bf16x8*)&ps[((rt << 4) + fr) * 88 + (ks << 5) + fko];
#pragma unroll
      for (int dt = 0; dt < 4; ++dt)
        bv[dt] = *(const bf16x8*)&Vts[(((dt << 4) + fr) << 6) + ccol];
#pragma unroll
      for (int rt = 0; rt < 2; ++rt)
#pragma unroll
        for (int dt = 0; dt < 4; ++dt)
          O[rt][dt] = __builtin_amdgcn_mfma_f32_16x16x32_bf16(af[rt], bv[dt], O[rt][dt], 0, 0, 0);
    }
    __syncthreads();   // protect Ks/Vts before next staging
  }

  // epilogue: normalize + scrambled write
#pragma unroll
  for (int rt = 0; rt < 2; ++rt)
#pragma unroll
    for (int r = 0; r < 4; ++r) {
      const float inv = 1.f / lrun[rt][r];
      const int q = qw + (rt << 4) + (quad << 2) + r;
      u16* orow = vecS + (size_t)((mb << 10) + q) * 1024 + (h_out << 6);
#pragma unroll
      for (int dt = 0; dt < 4; ++dt)
        orow[(dt << 4) + fr] = f2bf(O[rt][dt][r] * inv);
    }
}

// ---------------- LN fused with split-K(4) reduce: LN(X + sum(P)+bias) * mask ----------------
// XF32: residual X fp32 (else bf16). OUTF32: write fp32 (else bf16). HASB: add bias col vec.
template<bool XF32, bool OUTF32, bool HASB>
__global__ __launch_bounds__(256)
void ln_red4(const void* __restrict__ Xv, const u16* __restrict__ P0,
             const u16* __restrict__ P1, int MN,
             const float* __restrict__ bias,
             const float* __restrict__ g, const float* __restrict__ be,
             const float* __restrict__ maskf, void* __restrict__ outv) {
  const int r = blockIdx.x;
  const int tid = threadIdx.x;
  const size_t base = (size_t)r << 10;
  const float* Xf = (const float*)Xv;
  const u16* Xb = (const u16*)Xv;
  float x[4];
  float s1 = 0.f, s2 = 0.f;
#pragma unroll
  for (int j = 0; j < 4; ++j) {
    const int c = (tid << 2) + j;
    const size_t idx = base + c;
    float y = bf2f(P0[idx]) + bf2f(P1[idx]) + bf2f(P1[MN + idx]) + bf2f(P1[2 * (size_t)MN + idx]);
    if (HASB) y += bias[c];
    const float xv = XF32 ? Xf[idx] : bf2f(Xb[idx]);
    const float v = xv + y;
    x[j] = v; s1 += v; s2 += v * v;
  }
#pragma unroll
  for (int off = 32; off > 0; off >>= 1) { s1 += __shfl_xor(s1, off, 64); s2 += __shfl_xor(s2, off, 64); }
  __shared__ float rs1[4], rs2[4];
  if ((tid & 63) == 0) { rs1[tid >> 6] = s1; rs2[tid >> 6] = s2; }
  __syncthreads();
  s1 = rs1[0] + rs1[1] + rs1[2] + rs1[3];
  s2 = rs2[0] + rs2[1] + rs2[2] + rs2[3];
  const float mean = s1 * (1.f / 1024.f);
  const float var = s2 * (1.f / 1024.f) - mean * mean;
  const float rstd = rsqrtf(var + 1e-3f);
  const float mv = maskf[r];
#pragma unroll
  for (int j = 0; j < 4; ++j) {
    const int c = (tid << 2) + j;
    const float y = ((x[j] - mean) * rstd * g[c] + be[c]) * mv;
    if (OUTF32) ((float*)outv)[base + c] = y;
    else ((u16*)outv)[base + c] = f2bf(y);
  }
}

extern "C" void kernel_launch(void* const* d_in, const int* in_sizes, int n_in,
                              void* d_out, int out_size, void* d_ws, size_t ws_size,
                              hipStream_t stream) {
  (void)in_sizes; (void)n_in; (void)out_size; (void)ws_size;
  const float* dec  = (const float*)d_in[0];
  const unsigned char* mask = (const unsigned char*)d_in[1];
  const float* wqkv = (const float*)d_in[2];
  const float* bqkv = (const float*)d_in[3];
  const float* wo   = (const float*)d_in[4];
  const float* g1   = (const float*)d_in[5];
  const float* b1   = (const float*)d_in[6];
  const float* w1   = (const float*)d_in[7];
  const float* bc1  = (const float*)d_in[8];
  const float* w2   = (const float*)d_in[9];
  const float* bc2  = (const float*)d_in[10];
  const float* g2   = (const float*)d_in[11];
  const float* b2   = (const float*)d_in[12];
  char* ws = (char*)d_ws;
  // workspace layout (bytes), peak 117,506,048
  u16*   zp    = (u16*)(ws + 0);            // 16 KB zero page (pointer-increment safe)
  int*   pcnt  = (int*)(ws + 16384);
  float* maskf = (float*)(ws + 20480);      // [4096]
  int*   pidx  = (int*)(ws + 40960);        // [4][1024], ends 57344
  u16*   decB  = (u16*)(ws + 65536);        // [4096][1024]   ends 8454144   (dead after QKV gemm)
  u16*   wqkvT = (u16*)(ws + 8454144);      // [3072][1024]   ends 14745600  (dead after QKV gemm)
  u16*   woT   = (u16*)(ws + 14745600);     // [1024][1024]   ends 16842752  (dead after atto gemm)
  u16*   w1T   = (u16*)(ws + 16842752);     // [4096][3072]   ends 42008576  (dead after conv1)
  u16*   w2T   = (u16*)(ws + 42008576);     // [1024][12288]  ends 67174400
  u16*   qkv   = (u16*)(ws + 67174400);     // [4096][3072]   ends 92340224  (dead after attn)
  u16*   Vt    = (u16*)(ws + 92340224);     // [16*1024][512] ends 109117440 (dead after attn)
  u16*   vecS  = (u16*)(ws + 109117440);    // [4096][1024]   ends 117506048 (dead after atto gemm)
  u16*   x1bf  = (u16*)(ws + 8454144);      // reuses wqkvT region (written by LN1 after qkv dead)
  u16*   ybuf  = (u16*)(ws + 67174400);     // [4096][4096] reuses qkv+Vt (after LN1)
  // atto split-K partials (alive: after attn until LN1)
  u16*   aP0   = (u16*)(ws + 65536);        // kz=0, 8,388,608 B (decB region, dead)
  u16*   aP1   = (u16*)(ws + 67174400);     // kz=1..3, 3x8,388,608 B (qkv region, dead after attn)
  // conv2 split-K partials (alive: after conv2 until LN2)
  u16*   cP0   = (u16*)(ws + 65536);        // kz=0 (aP0 region, dead after LN1)
  u16*   cP1   = (u16*)(ws + 16842752);     // kz=1..3 (w1T region, dead after conv1)

  hipMemsetAsync(zp, 0, 16384, stream);
  compact_mask<<<dim3(4), dim3(64), 0, stream>>>(mask, pidx, pcnt, maskf);
  f32_to_bf16<<<dim3(4096), dim3(256), 0, stream>>>(dec, decB, 1048576);
  transpose_f32_bf16<<<dim3(48, 16), dim3(256), 0, stream>>>(wqkv, wqkvT, 1024, 3072);
  transpose_f32_bf16<<<dim3(16, 16), dim3(256), 0, stream>>>(wo, woT, 1024, 1024);
  transpose_f32_bf16<<<dim3(64, 48), dim3(256), 0, stream>>>(w1, w1T, 3072, 4096);
  transpose_f32_bf16<<<dim3(16, 192), dim3(256), 0, stream>>>(w2, w2T, 12288, 1024);
  // qkv = dec @ qkv_w + qkv_b
  gemm_bt<1, false, 1, 1024, 24><<<dim3(24, 32), dim3(256), 0, stream>>>(decB, wqkvT, bqkv, qkv, nullptr, 4096, 3072, zp);
  // attention (pad-keys-only MFMA flash, scrambled output)
  gather_v<<<dim3(16, 8), dim3(256), 0, stream>>>(qkv, pidx, pcnt, Vt);
  attn_mfma<<<dim3(64, 8), dim3(256), 0, stream>>>(qkv, Vt, pidx, pcnt, vecS);
  // attn_out partials = vecS @ o_w : split-K=4 (grid 8x32x4 = 1024 blocks)
  gemm_bt<1, false, 4, 1024, 8><<<dim3(8, 32, 4), dim3(256), 0, stream>>>(vecS, woT, nullptr, aP0, aP1, 4096, 1024, zp);
  // x1 = LN1(dec + sum(atto partials)) * mask  (fused reduce, no bias)
  ln_red4<true, false, false><<<dim3(4096), dim3(256), 0, stream>>>(dec, aP0, aP1, 4194304, nullptr, g1, b1, maskf, x1bf);
  // y = relu(conv1(x1))
  gemm_bt<3, true, 1, 1024, 32><<<dim3(32, 32), dim3(256), 0, stream>>>(x1bf, w1T, bc1, ybuf, nullptr, 4096, 4096, zp);
  // core partials = conv2(y): split-K=4 (grid 8x32x4 = 1024 blocks)
  gemm_bt<3, false, 4, 4096, 8><<<dim3(8, 32, 4), dim3(256), 0, stream>>>(ybuf, w2T, nullptr, cP0, cP1, 4096, 1024, zp);
  // out = LN2(x1 + sum(partials)+bias) * mask  -> fp32 d_out (fused reduce)
  ln_red4<false, true, true><<<dim3(4096), dim3(256), 0, stream>>>(x1bf, cP0, cP1, 4194304, bc2, g2, b2, maskf, (float*)d_out);
}